// Round 20
// baseline (165.446 us; speedup 1.0000x reference)
//
#include <hip/hip_runtime.h>

// MHA: BS=4 SEQ=2048 D_MODEL=1024 H=16 DH=64
// R20 = R19 + attn K/V staging converted to the same T4 counted-vmcnt gll16
// pipeline (prologue tiles 0,1; per tile: vmcnt(4)->s_barrier->compute->
// s_barrier->STAGE(kt+2)). gll16 addressing = R6's (data-proven); bq loads
// drained pre-loop so vmcnt counts are exact. qkv/gemm_out = R19 (proven).

typedef __attribute__((ext_vector_type(8))) unsigned short us8;
typedef __attribute__((ext_vector_type(4))) unsigned short us4;
typedef __attribute__((ext_vector_type(4))) int i4;
typedef __attribute__((ext_vector_type(4))) float f4;
typedef __attribute__((ext_vector_type(4))) float f32x4;
typedef __attribute__((ext_vector_type(8))) __bf16 bf16x8;
typedef __attribute__((ext_vector_type(2))) unsigned u32x2;
typedef __attribute__((ext_vector_type(4))) unsigned u32x4;

#define DEV static __device__ __forceinline__

DEV unsigned short f2bf(float f){
  unsigned u = __builtin_bit_cast(unsigned, f);
  u = (u + 0x7fffu + ((u >> 16) & 1u)) >> 16;
  return (unsigned short)u;
}

DEV bf16x8 ld_frag(const unsigned short* p){
  return __builtin_bit_cast(bf16x8, *(const us8*)p);
}

// async global->LDS, 16B per lane. LDS dest wave-uniform base + lane*16; global src per-lane.
DEV void gll16(const unsigned short* gsrc, unsigned short* ldst){
  __builtin_amdgcn_global_load_lds(
      (const __attribute__((address_space(1))) unsigned int*)gsrc,
      (__attribute__((address_space(3))) unsigned int*)ldst, 16, 0, 0);
}

// load 8 f32, convert to 8 bf16 via packed cvt (RNE)
DEV us8 ld_cvt_f32x8(const float* p){
  f4 v0 = *(const f4*)p;
  f4 v1 = *(const f4*)(p + 4);
  unsigned d0, d1, d2, d3;
  asm("v_cvt_pk_bf16_f32 %0, %1, %2" : "=v"(d0) : "v"(v0[0]), "v"(v0[1]));
  asm("v_cvt_pk_bf16_f32 %0, %1, %2" : "=v"(d1) : "v"(v0[2]), "v"(v0[3]));
  asm("v_cvt_pk_bf16_f32 %0, %1, %2" : "=v"(d2) : "v"(v1[0]), "v"(v1[1]));
  asm("v_cvt_pk_bf16_f32 %0, %1, %2" : "=v"(d3) : "v"(v1[2]), "v"(v1[3]));
  u32x4 u = {d0, d1, d2, d3};
  return __builtin_bit_cast(us8, u);
}

// ---------------- mask scan ----------------
__global__ __launch_bounds__(256) void mask_scan(
    const int* __restrict__ mask, int* __restrict__ idx, int* __restrict__ nk)
{
  const int b = blockIdx.x, t = threadIdx.x;
  __shared__ int sc[256];
  int m[8]; int c = 0;
#pragma unroll
  for(int r = 0; r < 8; ++r){ m[r] = mask[b * 2048 + t * 8 + r]; c += (m[r] != 0); }
  sc[t] = c;
  __syncthreads();
  for(int s = 1; s < 256; s <<= 1){
    int v = (t >= s) ? sc[t - s] : 0;
    __syncthreads();
    sc[t] += v;
    __syncthreads();
  }
  int pos = sc[t] - c;
  int total = sc[255];
#pragma unroll
  for(int r = 0; r < 8; ++r) if(m[r]) idx[b * 2048 + pos++] = t * 8 + r;
  int pend = (total + 127) & ~127;
  for(int p = total + t; p < pend; p += 256) idx[b * 2048 + p] = 0;
  if(t == 0) nk[b] = total;
}

// ---------------- one streaming conversion pass ----------------
__global__ __launch_bounds__(256) void cvt_all(
    const float* __restrict__ Wq, const float* __restrict__ Wk,
    const float* __restrict__ Wv, const float* __restrict__ Wo,
    const float* __restrict__ Qf, const float* __restrict__ Kf, const float* __restrict__ Vf,
    unsigned short* __restrict__ Wqb, unsigned short* __restrict__ Wkb,
    unsigned short* __restrict__ Wvb, unsigned short* __restrict__ Wob,
    unsigned short* __restrict__ Qb, unsigned short* __restrict__ Kbc,
    unsigned short* __restrict__ Vbc,
    const int* __restrict__ gidx, const int* __restrict__ nkarr)
{
  const int y = blockIdx.y, x = blockIdx.x, t = threadIdx.x;
  if(y < 4){
    if(x >= 512) return;
    const float* src = (y == 0) ? Wq : (y == 1) ? Wk : (y == 2) ? Wv : Wo;
    unsigned short* dst = (y == 0) ? Wqb : (y == 1) ? Wkb : (y == 2) ? Wvb : Wob;
    size_t i = (size_t)x * 2048 + t * 8;
    *(us8*)(dst + i) = ld_cvt_f32x8(src + i);
  } else if(y == 4){
    size_t i = (size_t)x * 2048 + t * 8;
    *(us8*)(Qb + i) = ld_cvt_f32x8(Qf + i);
  } else {
    const float* src = (y == 5) ? Kf : Vf;
    unsigned short* dst = (y == 5) ? Kbc : Vbc;
    int r0 = x * 2;
    int b = r0 >> 11, j = r0 & 2047;
    if(j >= ((nkarr[b] + 127) & ~127)) return;
    int rr = t >> 7;
    int srow = gidx[b * 2048 + j + rr];
    int col = (t & 127) * 8;
    *(us8*)(dst + (size_t)(r0 + rr) * 1024 + col) =
        ld_cvt_f32x8(src + ((size_t)b * 2048 + srow) * 1024 + col);
  }
}

// ---------------- Fused Q/K/V projection, 2-deep counted-vmcnt pipeline ----------------
__global__ __launch_bounds__(256) void qkv_proj(
    const unsigned short* __restrict__ Qb, const unsigned short* __restrict__ Kbc,
    const unsigned short* __restrict__ Vbc,
    const unsigned short* __restrict__ Wqb, const unsigned short* __restrict__ Wkb,
    const unsigned short* __restrict__ Wvb,
    const float* __restrict__ bq, const float* __restrict__ bk, const float* __restrict__ bv,
    unsigned short* __restrict__ qs, unsigned short* __restrict__ ksc,
    unsigned short* __restrict__ vTc, float qscale, const int* __restrict__ nkarr)
{
  __shared__ __align__(16) unsigned short As[2][128 * 64];
  __shared__ __align__(16) unsigned short Bs[2][128 * 64];
  const int tid = threadIdx.x;
  const int x = blockIdx.x, z = blockIdx.y >> 3, ny = blockIdx.y & 7;
  const int w = tid >> 6, l = tid & 63, g = l >> 4, l15 = l & 15;
  const int wm = w >> 1, wn = w & 1;
  const int xsw = ((l & 7) ^ (l >> 3)) << 3;

  if(z >= 1){
    const int gb = (x * 128) >> 11, j0 = (x * 128) & 2047;
    if(j0 >= ((nkarr[gb] + 127) & ~127)) return;    // uniform exit, pre-barrier
  }

  const unsigned short* Ab = (z == 0) ? Qb : (z == 1) ? Kbc : Wvb;
  const unsigned short* Bb = (z == 0) ? Wqb : (z == 1) ? Wkb : Vbc;
  const int abase = (z == 2) ? ny * 128 : x * 128;
  const int bbase = (z == 2) ? x * 128 : ny * 128;
  const int lrow = (w << 5) + (l >> 3);

  f32x4 acc[4][4];
#pragma unroll
  for(int a = 0; a < 4; ++a)
#pragma unroll
    for(int b = 0; b < 4; ++b) acc[a][b] = (f32x4){0.f,0.f,0.f,0.f};

  auto STAGE = [&](int kt, int nb){   // 8 gll16 per wave
#pragma unroll
    for(int j = 0; j < 4; ++j)
      gll16(Ab + (size_t)(abase + lrow + (j << 3)) * 1024 + kt * 64 + xsw,
            &As[nb][((w << 5) + (j << 3)) << 6]);
#pragma unroll
    for(int j = 0; j < 4; ++j)
      gll16(Bb + (size_t)(bbase + lrow + (j << 3)) * 1024 + kt * 64 + xsw,
            &Bs[nb][((w << 5) + (j << 3)) << 6]);
  };

  STAGE(0, 0);
  STAGE(1, 1);

  for(int kt = 0; kt < 16; ++kt){
    const int cur = kt & 1;
    if(kt + 1 < 16) asm volatile("s_waitcnt vmcnt(8)" ::: "memory");
    else            asm volatile("s_waitcnt vmcnt(0)" ::: "memory");
    __builtin_amdgcn_sched_barrier(0);
    __builtin_amdgcn_s_barrier();       // all waves' tile-kt loads landed
    __builtin_amdgcn_sched_barrier(0);
#pragma unroll
    for(int kk = 0; kk < 2; ++kk){
      bf16x8 af[4], bg[4];
#pragma unroll
      for(int mi = 0; mi < 4; ++mi){
        int row = wm * 64 + mi * 16 + l15;
        af[mi] = ld_frag(&As[cur][row * 64 + ((kk * 32 + g * 8) ^ ((row & 7) << 3))]);
      }
#pragma unroll
      for(int ni = 0; ni < 4; ++ni){
        int row = wn * 64 + ni * 16 + l15;
        bg[ni] = ld_frag(&Bs[cur][row * 64 + ((kk * 32 + g * 8) ^ ((row & 7) << 3))]);
      }
#pragma unroll
      for(int mi = 0; mi < 4; ++mi)
#pragma unroll
        for(int ni = 0; ni < 4; ++ni)
          acc[mi][ni] = __builtin_amdgcn_mfma_f32_16x16x32_bf16(af[mi], bg[ni], acc[mi][ni], 0, 0, 0);
    }
    __builtin_amdgcn_sched_barrier(0);
    __builtin_amdgcn_s_barrier();       // all waves done reading buf[cur]
    __builtin_amdgcn_sched_barrier(0);
    if(kt + 2 < 16) STAGE(kt + 2, cur);
  }

  if(z < 2){
    const float scale = (z == 0) ? qscale : 1.0f;
    const float* bias = (z == 0) ? bq : bk;
    unsigned short* out = (z == 0) ? qs : ksc;
#pragma unroll
    for(int mi = 0; mi < 4; ++mi)
#pragma unroll
      for(int ni = 0; ni < 4; ++ni){
        int gmb = x * 128 + wm * 64 + mi * 16 + g * 4;
        int gn  = ny * 128 + wn * 64 + ni * 16 + l15;
#pragma unroll
        for(int r = 0; r < 4; ++r){
          int gm = gmb + r;
          float v = (acc[mi][ni][r] + bias[gn]) * scale;
          int b = gm >> 11, s = gm & 2047, h = gn >> 6, dh = gn & 63;
          out[(size_t)(((b << 4) + h) * 2048 + s) * 64 + dh] = f2bf(v);
        }
      }
  } else {
#pragma unroll
    for(int mi = 0; mi < 4; ++mi)
#pragma unroll
      for(int ni = 0; ni < 4; ++ni){
        int gmb = ny * 128 + wm * 64 + mi * 16 + g * 4;   // d index
        int gn  = x * 128 + wn * 64 + ni * 16 + l15;      // compacted s index
#pragma unroll
        for(int r = 0; r < 4; ++r){
          int gm = gmb + r;
          float v = acc[mi][ni][r] + bv[gm];
          int h = gm >> 6, dh = gm & 63, b = gn >> 11, s = gn & 2047;
          vTc[(size_t)(((b << 4) + h) * 64 + dh) * 2048 + s] = f2bf(v);
        }
      }
  }
}

// ---------------- out-proj GEMM, 2-deep counted-vmcnt pipeline (SWAPG) ----------------
__global__ __launch_bounds__(256) void gemm_out(
    const unsigned short* __restrict__ Ap, const unsigned short* __restrict__ Bp,
    const float* __restrict__ bias, float* __restrict__ outp, int K)
{
  __shared__ __align__(16) unsigned short As[2][128 * 64];
  __shared__ __align__(16) unsigned short Bs[2][128 * 64];
  const int tid = threadIdx.x;
  const int gy = blockIdx.x, gx = blockIdx.y;      // SWAPG: M-tile = x
  const int w = tid >> 6, l = tid & 63, g = l >> 4, l15 = l & 15;
  const int wm = w >> 1, wn = w & 1;
  const int xsw = ((l & 7) ^ (l >> 3)) << 3;
  const int lrow = (w << 5) + (l >> 3);

  f32x4 acc[4][4];
#pragma unroll
  for(int a = 0; a < 4; ++a)
#pragma unroll
    for(int b = 0; b < 4; ++b) acc[a][b] = (f32x4){0.f,0.f,0.f,0.f};

  auto STAGE = [&](int kt, int nb){   // 8 gll16 per wave
#pragma unroll
    for(int j = 0; j < 4; ++j)
      gll16(Ap + (size_t)(gy * 128 + lrow + (j << 3)) * K + kt * 64 + xsw,
            &As[nb][((w << 5) + (j << 3)) << 6]);
#pragma unroll
    for(int j = 0; j < 4; ++j)
      gll16(Bp + (size_t)(gx * 128 + lrow + (j << 3)) * K + kt * 64 + xsw,
            &Bs[nb][((w << 5) + (j << 3)) << 6]);
  };

  const int nkt = K >> 6;
  STAGE(0, 0);
  STAGE(1, 1);

  for(int kt = 0; kt < nkt; ++kt){
    const int cur = kt & 1;
    if(kt + 1 < nkt) asm volatile("s_waitcnt vmcnt(8)" ::: "memory");
    else             asm volatile("s_waitcnt vmcnt(0)" ::: "memory");
    __builtin_amdgcn_sched_barrier(0);
    __builtin_amdgcn_s_barrier();
    __builtin_amdgcn_sched_barrier(0);
#pragma unroll
    for(int kk = 0; kk < 2; ++kk){
      bf16x8 af[4], bg[4];
#pragma unroll
      for(int mi = 0; mi < 4; ++mi){
        int row = wm * 64 + mi * 16 + l15;
        af[mi] = ld_frag(&As[cur][row * 64 + ((kk * 32 + g * 8) ^ ((row & 7) << 3))]);
      }
#pragma unroll
      for(int ni = 0; ni < 4; ++ni){
        int row = wn * 64 + ni * 16 + l15;
        bg[ni] = ld_frag(&Bs[cur][row * 64 + ((kk * 32 + g * 8) ^ ((row & 7) << 3))]);
      }
#pragma unroll
      for(int mi = 0; mi < 4; ++mi)
#pragma unroll
        for(int ni = 0; ni < 4; ++ni)
          acc[mi][ni] = __builtin_amdgcn_mfma_f32_16x16x32_bf16(af[mi], bg[ni], acc[mi][ni], 0, 0, 0);
    }
    __builtin_amdgcn_sched_barrier(0);
    __builtin_amdgcn_s_barrier();
    __builtin_amdgcn_sched_barrier(0);
    if(kt + 2 < nkt) STAGE(kt + 2, cur);
  }

#pragma unroll
  for(int mi = 0; mi < 4; ++mi)
#pragma unroll
    for(int ni = 0; ni < 4; ++ni){
      int gmb = gy * 128 + wm * 64 + mi * 16 + g * 4;
      int gn  = gx * 128 + wn * 64 + ni * 16 + l15;
#pragma unroll
      for(int r = 0; r < 4; ++r)
        outp[(size_t)(gmb + r) * 1024 + gn] = acc[mi][ni][r] + bias[gn];
    }
}

// ---------------- Flash attention, counted-vmcnt gll16 pipeline ----------------
__global__ __launch_bounds__(256) void attn_kernel(
    const unsigned short* __restrict__ q, const unsigned short* __restrict__ ksc,
    const unsigned short* __restrict__ vTc, const int* __restrict__ nk,
    unsigned short* __restrict__ ctx)
{
  __shared__ __align__(16) unsigned short KsB[2][64 * 64];
  __shared__ __align__(16) unsigned short VtB[2][64 * 64];
  __shared__ __align__(16) unsigned short Ps[4][16 * 64];

  const int bh = blockIdx.x;            // bh fastest -> XCD co-location
  const int qt = blockIdx.y;
  const int b  = bh >> 4, h = bh & 15;
  const int tid = threadIdx.x;
  const int w = tid >> 6, l = tid & 63, g = l >> 4, l15 = l & 15;

  const int nkb = nk[b];
  const int nt = (nkb + 63) >> 6;

  const unsigned short* qbase = q + ((size_t)(bh * 2048 + qt * 64 + w * 16 + l15)) * 64;
  bf16x8 bq[2];
  bq[0] = ld_frag(qbase + g * 8);
  bq[1] = ld_frag(qbase + 32 + g * 8);

  const unsigned short* kbase = ksc + (size_t)bh * 2048 * 64;
  const unsigned short* vbase = vTc + (size_t)bh * 64 * 2048;

  // gll16 staging (R6-proven addressing): pre-swizzled global src, linear LDS
  const int xsw = ((l & 7) ^ (l >> 3)) << 3;
  const unsigned short* kg0 = kbase + (size_t)((w << 4) + (l >> 3)) * 64 + xsw;
  const unsigned short* vg0 = vbase + (size_t)((w << 4) + (l >> 3)) * 2048 + xsw;
  const int kofs = (w << 4) << 6;

#define STAGE(kt_, bb_) do{                                            \
    const unsigned short* kg_ = kg0 + (size_t)(kt_) * 4096;            \
    const unsigned short* vg_ = vg0 + (size_t)(kt_) * 64;              \
    gll16(kg_, &KsB[bb_][kofs]); gll16(kg_ + 512, &KsB[bb_][kofs + 512]); \
    gll16(vg_, &VtB[bb_][kofs]); gll16(vg_ + 8 * 2048, &VtB[bb_][kofs + 512]); \
  }while(0)

  f32x4 acc[4];
#pragma unroll
  for(int mi = 0; mi < 4; ++mi) acc[mi] = (f32x4){0.f,0.f,0.f,0.f};
  float ll = 0.f;

  // drain bq (and any prior vmem) so vmcnt counts purely staging ops
  asm volatile("s_waitcnt vmcnt(0)" ::: "memory");
  STAGE(0, 0);
  if(nt > 1) STAGE(1, 1);

  for(int kt = 0; kt < nt; ++kt){
    const int cur = kt & 1;
    if(kt + 1 < nt) asm volatile("s_waitcnt vmcnt(4)" ::: "memory");
    else            asm volatile("s_waitcnt vmcnt(0)" ::: "memory");
    __builtin_amdgcn_sched_barrier(0);
    __builtin_amdgcn_s_barrier();       // tile-kt K/V landed for all waves
    __builtin_amdgcn_sched_barrier(0);

    f32x4 sa[4];
#pragma unroll
    for(int mi = 0; mi < 4; ++mi) sa[mi] = (f32x4){0.f,0.f,0.f,0.f};
    __builtin_amdgcn_s_setprio(1);
#pragma unroll
    for(int kk = 0; kk < 2; ++kk){
#pragma unroll
      for(int mi = 0; mi < 4; ++mi){
        int row = mi * 16 + l15;
        bf16x8 af = ld_frag(&KsB[cur][row * 64 + ((kk * 32 + g * 8) ^ ((row & 7) << 3))]);
        sa[mi] = __builtin_amdgcn_mfma_f32_16x16x32_bf16(af, bq[kk], sa[mi], 0, 0, 0);
      }
    }
    __builtin_amdgcn_s_setprio(0);

    float p[4][4];
    if((kt + 1) * 64 <= nkb){
#pragma unroll
      for(int mi = 0; mi < 4; ++mi)
#pragma unroll
        for(int r = 0; r < 4; ++r){
          p[mi][r] = __builtin_amdgcn_exp2f(sa[mi][r]);
          ll += p[mi][r];
        }
    } else {
      int kb0 = kt * 64 + g * 4;
#pragma unroll
      for(int mi = 0; mi < 4; ++mi)
#pragma unroll
        for(int r = 0; r < 4; ++r){
          float e = __builtin_amdgcn_exp2f(sa[mi][r]);
          p[mi][r] = (kb0 + mi * 16 + r < nkb) ? e : 0.f;
          ll += p[mi][r];
        }
    }

#pragma unroll
    for(int mi = 0; mi < 4; ++mi){
      unsigned d0, d1;
      asm("v_cvt_pk_bf16_f32 %0, %1, %2" : "=v"(d0) : "v"(p[mi][0]), "v"(p[mi][1]));
      asm("v_cvt_pk_bf16_f32 %0, %1, %2" : "=v"(d1) : "v"(p[mi][2]), "v"(p[mi][3]));
      u32x2 dd = {d0, d1};
      *(u32x2*)&Ps[w][l15 * 64 + ((mi * 16 + g * 4) ^ ((l15 & 7) << 3))] = dd;
    }

    __builtin_amdgcn_s_setprio(1);
#pragma unroll
    for(int kk = 0; kk < 2; ++kk){
      bf16x8 pb = ld_frag(&Ps[w][l15 * 64 + ((kk * 32 + g * 8) ^ ((l15 & 7) << 3))]);
#pragma unroll
      for(int mi = 0; mi < 4; ++mi){
        int row = mi * 16 + l15;
        bf16x8 av = ld_frag(&VtB[cur][row * 64 + ((kk * 32 + g * 8) ^ ((row & 7) << 3))]);
        acc[mi] = __builtin_amdgcn_mfma_f32_16x16x32_bf16(av, pb, acc[mi], 0, 0, 0);
      }
    }
    __builtin_amdgcn_s_setprio(0);

    __builtin_amdgcn_sched_barrier(0);
    __builtin_amdgcn_s_barrier();       // all waves done reading buf[cur]
    __builtin_amdgcn_sched_barrier(0);
    if(kt + 2 < nt) STAGE(kt + 2, cur);
  }

  ll += __shfl_xor(ll, 16);
  ll += __shfl_xor(ll, 32);
  float inv = 1.0f / ll;

  {
    int qrow = w * 16 + l15;
#pragma unroll
    for(int mi = 0; mi < 4; ++mi){
      us4 o;
#pragma unroll
      for(int r = 0; r < 4; ++r) o[r] = f2bf(acc[mi][r] * inv);
      *(us4*)&KsB[0][qrow * 64 + ((mi * 16 + g * 4) ^ ((qrow & 7) << 3))] = o;
    }
  }
  __syncthreads();
  {
    int qrow = tid >> 2, part = tid & 3;
    us8 v0 = *(const us8*)&KsB[0][qrow * 64 + ((part * 16)     ^ ((qrow & 7) << 3))];
    us8 v1 = *(const us8*)&KsB[0][qrow * 64 + ((part * 16 + 8) ^ ((qrow & 7) << 3))];
    size_t orow = ((size_t)b * 2048 + qt * 64 + qrow) * 1024 + h * 64 + part * 16;
    *(us8*)&ctx[orow] = v0;
    *(us8*)&ctx[orow + 8] = v1;
  }
#undef STAGE
}

// ---------------- launch ----------------
extern "C" void kernel_launch(void* const* d_in, const int* in_sizes, int n_in,
                              void* d_out, int out_size, void* d_ws, size_t ws_size,
                              hipStream_t stream) {
  const float* Qf = (const float*)d_in[0];
  const float* Kf = (const float*)d_in[1];
  const float* Vf = (const float*)d_in[2];
  const int*   Mk = (const int*)d_in[3];
  const float* Wq = (const float*)d_in[4];
  const float* bq = (const float*)d_in[5];
  const float* Wk = (const float*)d_in[6];
  const float* bk = (const float*)d_in[7];
  const float* Wv = (const float*)d_in[8];
  const float* bv = (const float*)d_in[9];
  const float* Wo = (const float*)d_in[10];
  const float* bo = (const float*)d_in[11];

  const size_t MB = 1u << 20;
  char* ws = (char*)d_ws;
  unsigned short* Wqb = (unsigned short*)(ws + 0 * MB);
  unsigned short* Wkb = (unsigned short*)(ws + 2 * MB);
  unsigned short* Wvb = (unsigned short*)(ws + 4 * MB);
  unsigned short* Wob = (unsigned short*)(ws + 6 * MB);
  unsigned short* qs  = (unsigned short*)(ws + 8 * MB);
  unsigned short* ksc = (unsigned short*)(ws + 24 * MB);
  unsigned short* vTc = (unsigned short*)(ws + 40 * MB);
  unsigned short* ctx = (unsigned short*)(ws + 56 * MB);
  int* idx = (int*)(ws + 72 * MB);
  int* nk  = (int*)(ws + 73 * MB);
  unsigned short* Qb  = (unsigned short*)(ws + 74 * MB);
  unsigned short* Kbc = (unsigned short*)(ws + 90 * MB);
  unsigned short* Vbc = (unsigned short*)(ws + 106 * MB);

  mask_scan<<<4, 256, 0, stream>>>(Mk, idx, nk);
  cvt_all<<<dim3(4096, 7), 256, 0, stream>>>(Wq, Wk, Wv, Wo, Qf, Kf, Vf,
                                             Wqb, Wkb, Wvb, Wob, Qb, Kbc, Vbc,
                                             idx, nk);

  const float QSCALE = 0.125f * 1.4426950408889634f;  // 1/sqrt(d_head) * log2(e)
  dim3 blk(256);
  qkv_proj<<<dim3(64, 24), blk, 0, stream>>>(Qb, Kbc, Vbc, Wqb, Wkb, Wvb,
                                             bq, bk, bv, qs, ksc, vTc, QSCALE, nk);
  attn_kernel<<<dim3(64, 32), blk, 0, stream>>>(qs, ksc, vTc, nk, ctx);
  gemm_out<<<dim3(64, 8), blk, 0, stream>>>(ctx, Wob, bo, (float*)d_out, 1024);
}

// Round 21
// 159.794 us; speedup vs baseline: 1.0354x; 1.0354x over previous
//
#include <hip/hip_runtime.h>

// MHA: BS=4 SEQ=2048 D_MODEL=1024 H=16 DH=64
// R21 = R19/R20 base + attn widened to 512-thread / 8-wave blocks:
//   each block owns 128 q-rows (wave w -> rows w*16..+15, all PARALLEL —
//   fixes R17's serialization); K/V staged once per tile for 2x q-rows
//   (1 gll16/lane K + 1 V = exact 8KB tile); counted-vmcnt pipeline
//   (vmcnt(2) steady). LDS 48KB -> 3 blocks/CU = 24 waves/CU.
// qkv_proj / gemm_out: R19 counted-vmcnt pipelines (proven).

typedef __attribute__((ext_vector_type(8))) unsigned short us8;
typedef __attribute__((ext_vector_type(4))) unsigned short us4;
typedef __attribute__((ext_vector_type(4))) int i4;
typedef __attribute__((ext_vector_type(4))) float f4;
typedef __attribute__((ext_vector_type(4))) float f32x4;
typedef __attribute__((ext_vector_type(8))) __bf16 bf16x8;
typedef __attribute__((ext_vector_type(2))) unsigned u32x2;
typedef __attribute__((ext_vector_type(4))) unsigned u32x4;

#define DEV static __device__ __forceinline__

DEV unsigned short f2bf(float f){
  unsigned u = __builtin_bit_cast(unsigned, f);
  u = (u + 0x7fffu + ((u >> 16) & 1u)) >> 16;
  return (unsigned short)u;
}

DEV bf16x8 ld_frag(const unsigned short* p){
  return __builtin_bit_cast(bf16x8, *(const us8*)p);
}

// async global->LDS, 16B per lane. LDS dest wave-uniform base + lane*16; global src per-lane.
DEV void gll16(const unsigned short* gsrc, unsigned short* ldst){
  __builtin_amdgcn_global_load_lds(
      (const __attribute__((address_space(1))) unsigned int*)gsrc,
      (__attribute__((address_space(3))) unsigned int*)ldst, 16, 0, 0);
}

// load 8 f32, convert to 8 bf16 via packed cvt (RNE)
DEV us8 ld_cvt_f32x8(const float* p){
  f4 v0 = *(const f4*)p;
  f4 v1 = *(const f4*)(p + 4);
  unsigned d0, d1, d2, d3;
  asm("v_cvt_pk_bf16_f32 %0, %1, %2" : "=v"(d0) : "v"(v0[0]), "v"(v0[1]));
  asm("v_cvt_pk_bf16_f32 %0, %1, %2" : "=v"(d1) : "v"(v0[2]), "v"(v0[3]));
  asm("v_cvt_pk_bf16_f32 %0, %1, %2" : "=v"(d2) : "v"(v1[0]), "v"(v1[1]));
  asm("v_cvt_pk_bf16_f32 %0, %1, %2" : "=v"(d3) : "v"(v1[2]), "v"(v1[3]));
  u32x4 u = {d0, d1, d2, d3};
  return __builtin_bit_cast(us8, u);
}

// ---------------- mask scan ----------------
__global__ __launch_bounds__(256) void mask_scan(
    const int* __restrict__ mask, int* __restrict__ idx, int* __restrict__ nk)
{
  const int b = blockIdx.x, t = threadIdx.x;
  __shared__ int sc[256];
  int m[8]; int c = 0;
#pragma unroll
  for(int r = 0; r < 8; ++r){ m[r] = mask[b * 2048 + t * 8 + r]; c += (m[r] != 0); }
  sc[t] = c;
  __syncthreads();
  for(int s = 1; s < 256; s <<= 1){
    int v = (t >= s) ? sc[t - s] : 0;
    __syncthreads();
    sc[t] += v;
    __syncthreads();
  }
  int pos = sc[t] - c;
  int total = sc[255];
#pragma unroll
  for(int r = 0; r < 8; ++r) if(m[r]) idx[b * 2048 + pos++] = t * 8 + r;
  int pend = (total + 127) & ~127;
  for(int p = total + t; p < pend; p += 256) idx[b * 2048 + p] = 0;
  if(t == 0) nk[b] = total;
}

// ---------------- one streaming conversion pass ----------------
__global__ __launch_bounds__(256) void cvt_all(
    const float* __restrict__ Wq, const float* __restrict__ Wk,
    const float* __restrict__ Wv, const float* __restrict__ Wo,
    const float* __restrict__ Qf, const float* __restrict__ Kf, const float* __restrict__ Vf,
    unsigned short* __restrict__ Wqb, unsigned short* __restrict__ Wkb,
    unsigned short* __restrict__ Wvb, unsigned short* __restrict__ Wob,
    unsigned short* __restrict__ Qb, unsigned short* __restrict__ Kbc,
    unsigned short* __restrict__ Vbc,
    const int* __restrict__ gidx, const int* __restrict__ nkarr)
{
  const int y = blockIdx.y, x = blockIdx.x, t = threadIdx.x;
  if(y < 4){
    if(x >= 512) return;
    const float* src = (y == 0) ? Wq : (y == 1) ? Wk : (y == 2) ? Wv : Wo;
    unsigned short* dst = (y == 0) ? Wqb : (y == 1) ? Wkb : (y == 2) ? Wvb : Wob;
    size_t i = (size_t)x * 2048 + t * 8;
    *(us8*)(dst + i) = ld_cvt_f32x8(src + i);
  } else if(y == 4){
    size_t i = (size_t)x * 2048 + t * 8;
    *(us8*)(Qb + i) = ld_cvt_f32x8(Qf + i);
  } else {
    const float* src = (y == 5) ? Kf : Vf;
    unsigned short* dst = (y == 5) ? Kbc : Vbc;
    int r0 = x * 2;
    int b = r0 >> 11, j = r0 & 2047;
    if(j >= ((nkarr[b] + 127) & ~127)) return;
    int rr = t >> 7;
    int srow = gidx[b * 2048 + j + rr];
    int col = (t & 127) * 8;
    *(us8*)(dst + (size_t)(r0 + rr) * 1024 + col) =
        ld_cvt_f32x8(src + ((size_t)b * 2048 + srow) * 1024 + col);
  }
}

// ---------------- Fused Q/K/V projection, 2-deep counted-vmcnt pipeline ----------------
__global__ __launch_bounds__(256) void qkv_proj(
    const unsigned short* __restrict__ Qb, const unsigned short* __restrict__ Kbc,
    const unsigned short* __restrict__ Vbc,
    const unsigned short* __restrict__ Wqb, const unsigned short* __restrict__ Wkb,
    const unsigned short* __restrict__ Wvb,
    const float* __restrict__ bq, const float* __restrict__ bk, const float* __restrict__ bv,
    unsigned short* __restrict__ qs, unsigned short* __restrict__ ksc,
    unsigned short* __restrict__ vTc, float qscale, const int* __restrict__ nkarr)
{
  __shared__ __align__(16) unsigned short As[2][128 * 64];
  __shared__ __align__(16) unsigned short Bs[2][128 * 64];
  const int tid = threadIdx.x;
  const int x = blockIdx.x, z = blockIdx.y >> 3, ny = blockIdx.y & 7;
  const int w = tid >> 6, l = tid & 63, g = l >> 4, l15 = l & 15;
  const int wm = w >> 1, wn = w & 1;
  const int xsw = ((l & 7) ^ (l >> 3)) << 3;

  if(z >= 1){
    const int gb = (x * 128) >> 11, j0 = (x * 128) & 2047;
    if(j0 >= ((nkarr[gb] + 127) & ~127)) return;    // uniform exit, pre-barrier
  }

  const unsigned short* Ab = (z == 0) ? Qb : (z == 1) ? Kbc : Wvb;
  const unsigned short* Bb = (z == 0) ? Wqb : (z == 1) ? Wkb : Vbc;
  const int abase = (z == 2) ? ny * 128 : x * 128;
  const int bbase = (z == 2) ? x * 128 : ny * 128;
  const int lrow = (w << 5) + (l >> 3);

  f32x4 acc[4][4];
#pragma unroll
  for(int a = 0; a < 4; ++a)
#pragma unroll
    for(int b = 0; b < 4; ++b) acc[a][b] = (f32x4){0.f,0.f,0.f,0.f};

  auto STAGE = [&](int kt, int nb){   // 8 gll16 per wave
#pragma unroll
    for(int j = 0; j < 4; ++j)
      gll16(Ab + (size_t)(abase + lrow + (j << 3)) * 1024 + kt * 64 + xsw,
            &As[nb][((w << 5) + (j << 3)) << 6]);
#pragma unroll
    for(int j = 0; j < 4; ++j)
      gll16(Bb + (size_t)(bbase + lrow + (j << 3)) * 1024 + kt * 64 + xsw,
            &Bs[nb][((w << 5) + (j << 3)) << 6]);
  };

  STAGE(0, 0);
  STAGE(1, 1);

  for(int kt = 0; kt < 16; ++kt){
    const int cur = kt & 1;
    if(kt + 1 < 16) asm volatile("s_waitcnt vmcnt(8)" ::: "memory");
    else            asm volatile("s_waitcnt vmcnt(0)" ::: "memory");
    __builtin_amdgcn_sched_barrier(0);
    __builtin_amdgcn_s_barrier();       // all waves' tile-kt loads landed
    __builtin_amdgcn_sched_barrier(0);
#pragma unroll
    for(int kk = 0; kk < 2; ++kk){
      bf16x8 af[4], bg[4];
#pragma unroll
      for(int mi = 0; mi < 4; ++mi){
        int row = wm * 64 + mi * 16 + l15;
        af[mi] = ld_frag(&As[cur][row * 64 + ((kk * 32 + g * 8) ^ ((row & 7) << 3))]);
      }
#pragma unroll
      for(int ni = 0; ni < 4; ++ni){
        int row = wn * 64 + ni * 16 + l15;
        bg[ni] = ld_frag(&Bs[cur][row * 64 + ((kk * 32 + g * 8) ^ ((row & 7) << 3))]);
      }
#pragma unroll
      for(int mi = 0; mi < 4; ++mi)
#pragma unroll
        for(int ni = 0; ni < 4; ++ni)
          acc[mi][ni] = __builtin_amdgcn_mfma_f32_16x16x32_bf16(af[mi], bg[ni], acc[mi][ni], 0, 0, 0);
    }
    __builtin_amdgcn_sched_barrier(0);
    __builtin_amdgcn_s_barrier();       // all waves done reading buf[cur]
    __builtin_amdgcn_sched_barrier(0);
    if(kt + 2 < 16) STAGE(kt + 2, cur);
  }

  if(z < 2){
    const float scale = (z == 0) ? qscale : 1.0f;
    const float* bias = (z == 0) ? bq : bk;
    unsigned short* out = (z == 0) ? qs : ksc;
#pragma unroll
    for(int mi = 0; mi < 4; ++mi)
#pragma unroll
      for(int ni = 0; ni < 4; ++ni){
        int gmb = x * 128 + wm * 64 + mi * 16 + g * 4;
        int gn  = ny * 128 + wn * 64 + ni * 16 + l15;
#pragma unroll
        for(int r = 0; r < 4; ++r){
          int gm = gmb + r;
          float v = (acc[mi][ni][r] + bias[gn]) * scale;
          int b = gm >> 11, s = gm & 2047, h = gn >> 6, dh = gn & 63;
          out[(size_t)(((b << 4) + h) * 2048 + s) * 64 + dh] = f2bf(v);
        }
      }
  } else {
#pragma unroll
    for(int mi = 0; mi < 4; ++mi)
#pragma unroll
      for(int ni = 0; ni < 4; ++ni){
        int gmb = ny * 128 + wm * 64 + mi * 16 + g * 4;   // d index
        int gn  = x * 128 + wn * 64 + ni * 16 + l15;      // compacted s index
#pragma unroll
        for(int r = 0; r < 4; ++r){
          int gm = gmb + r;
          float v = acc[mi][ni][r] + bv[gm];
          int h = gm >> 6, dh = gm & 63, b = gn >> 11, s = gn & 2047;
          vTc[(size_t)(((b << 4) + h) * 64 + dh) * 2048 + s] = f2bf(v);
        }
      }
  }
}

// ---------------- out-proj GEMM, 2-deep counted-vmcnt pipeline (SWAPG) ----------------
__global__ __launch_bounds__(256) void gemm_out(
    const unsigned short* __restrict__ Ap, const unsigned short* __restrict__ Bp,
    const float* __restrict__ bias, float* __restrict__ outp, int K)
{
  __shared__ __align__(16) unsigned short As[2][128 * 64];
  __shared__ __align__(16) unsigned short Bs[2][128 * 64];
  const int tid = threadIdx.x;
  const int gy = blockIdx.x, gx = blockIdx.y;      // SWAPG: M-tile = x
  const int w = tid >> 6, l = tid & 63, g = l >> 4, l15 = l & 15;
  const int wm = w >> 1, wn = w & 1;
  const int xsw = ((l & 7) ^ (l >> 3)) << 3;
  const int lrow = (w << 5) + (l >> 3);

  f32x4 acc[4][4];
#pragma unroll
  for(int a = 0; a < 4; ++a)
#pragma unroll
    for(int b = 0; b < 4; ++b) acc[a][b] = (f32x4){0.f,0.f,0.f,0.f};

  auto STAGE = [&](int kt, int nb){   // 8 gll16 per wave
#pragma unroll
    for(int j = 0; j < 4; ++j)
      gll16(Ap + (size_t)(gy * 128 + lrow + (j << 3)) * K + kt * 64 + xsw,
            &As[nb][((w << 5) + (j << 3)) << 6]);
#pragma unroll
    for(int j = 0; j < 4; ++j)
      gll16(Bp + (size_t)(gx * 128 + lrow + (j << 3)) * K + kt * 64 + xsw,
            &Bs[nb][((w << 5) + (j << 3)) << 6]);
  };

  const int nkt = K >> 6;
  STAGE(0, 0);
  STAGE(1, 1);

  for(int kt = 0; kt < nkt; ++kt){
    const int cur = kt & 1;
    if(kt + 1 < nkt) asm volatile("s_waitcnt vmcnt(8)" ::: "memory");
    else             asm volatile("s_waitcnt vmcnt(0)" ::: "memory");
    __builtin_amdgcn_sched_barrier(0);
    __builtin_amdgcn_s_barrier();
    __builtin_amdgcn_sched_barrier(0);
#pragma unroll
    for(int kk = 0; kk < 2; ++kk){
      bf16x8 af[4], bg[4];
#pragma unroll
      for(int mi = 0; mi < 4; ++mi){
        int row = wm * 64 + mi * 16 + l15;
        af[mi] = ld_frag(&As[cur][row * 64 + ((kk * 32 + g * 8) ^ ((row & 7) << 3))]);
      }
#pragma unroll
      for(int ni = 0; ni < 4; ++ni){
        int row = wn * 64 + ni * 16 + l15;
        bg[ni] = ld_frag(&Bs[cur][row * 64 + ((kk * 32 + g * 8) ^ ((row & 7) << 3))]);
      }
#pragma unroll
      for(int mi = 0; mi < 4; ++mi)
#pragma unroll
        for(int ni = 0; ni < 4; ++ni)
          acc[mi][ni] = __builtin_amdgcn_mfma_f32_16x16x32_bf16(af[mi], bg[ni], acc[mi][ni], 0, 0, 0);
    }
    __builtin_amdgcn_sched_barrier(0);
    __builtin_amdgcn_s_barrier();
    __builtin_amdgcn_sched_barrier(0);
    if(kt + 2 < nkt) STAGE(kt + 2, cur);
  }

#pragma unroll
  for(int mi = 0; mi < 4; ++mi)
#pragma unroll
    for(int ni = 0; ni < 4; ++ni){
      int gmb = gy * 128 + wm * 64 + mi * 16 + g * 4;
      int gn  = gx * 128 + wn * 64 + ni * 16 + l15;
#pragma unroll
      for(int r = 0; r < 4; ++r)
        outp[(size_t)(gmb + r) * 1024 + gn] = acc[mi][ni][r] + bias[gn];
    }
}

// ---------------- Flash attention, 8-wave blocks, counted-vmcnt pipeline ----------------
// grid (bh=64, qt=16), 512 threads. Wave w owns q rows qt*128 + w*16 .. +15.
// K/V tile (64x64) staged by all 8 waves: 1 gll16/lane K + 1 V (= 8KB each).
__global__ __launch_bounds__(512) void attn_kernel(
    const unsigned short* __restrict__ q, const unsigned short* __restrict__ ksc,
    const unsigned short* __restrict__ vTc, const int* __restrict__ nk,
    unsigned short* __restrict__ ctx)
{
  __shared__ __align__(16) unsigned short KsB[2][64 * 64];
  __shared__ __align__(16) unsigned short VtB[2][64 * 64];
  __shared__ __align__(16) unsigned short Ps[8][16 * 64];

  const int bh = blockIdx.x;            // bh fastest -> XCD co-location
  const int qt = blockIdx.y;            // 128-row q tile
  const int b  = bh >> 4, h = bh & 15;
  const int tid = threadIdx.x;
  const int w = tid >> 6, l = tid & 63, g = l >> 4, l15 = l & 15;

  const int nkb = nk[b];
  const int nt = (nkb + 63) >> 6;

  const unsigned short* qbase = q + ((size_t)(bh * 2048 + qt * 128 + w * 16 + l15)) * 64;
  bf16x8 bq[2];
  bq[0] = ld_frag(qbase + g * 8);
  bq[1] = ld_frag(qbase + 32 + g * 8);

  const unsigned short* kbase = ksc + (size_t)bh * 2048 * 64;
  const unsigned short* vbase = vTc + (size_t)bh * 64 * 2048;

  // staging: wave w covers rows w*8..w*8+7 of the 64-row tile (K: keys, V: d)
  const int xsw = ((l & 7) ^ (l >> 3)) << 3;
  const unsigned short* kg0 = kbase + (size_t)((w << 3) + (l >> 3)) * 64 + xsw;
  const unsigned short* vg0 = vbase + (size_t)((w << 3) + (l >> 3)) * 2048 + xsw;
  const int kofs = (w << 3) << 6;       // wave-uniform LDS base (8 rows)

#define STAGE(kt_, bb_) do{                                    \
    gll16(kg0 + (size_t)(kt_) * 4096, &KsB[bb_][kofs]);        \
    gll16(vg0 + (size_t)(kt_) * 64,   &VtB[bb_][kofs]);        \
  }while(0)

  f32x4 acc[4];
#pragma unroll
  for(int mi = 0; mi < 4; ++mi) acc[mi] = (f32x4){0.f,0.f,0.f,0.f};
  float ll = 0.f;

  // drain bq loads so vmcnt counts purely staging ops
  asm volatile("s_waitcnt vmcnt(0)" ::: "memory");
  STAGE(0, 0);
  if(nt > 1) STAGE(1, 1);

  for(int kt = 0; kt < nt; ++kt){
    const int cur = kt & 1;
    if(kt + 1 < nt) asm volatile("s_waitcnt vmcnt(2)" ::: "memory");
    else            asm volatile("s_waitcnt vmcnt(0)" ::: "memory");
    __builtin_amdgcn_sched_barrier(0);
    __builtin_amdgcn_s_barrier();       // tile-kt K/V landed for all waves
    __builtin_amdgcn_sched_barrier(0);

    f32x4 sa[4];
#pragma unroll
    for(int mi = 0; mi < 4; ++mi) sa[mi] = (f32x4){0.f,0.f,0.f,0.f};
    __builtin_amdgcn_s_setprio(1);
#pragma unroll
    for(int kk = 0; kk < 2; ++kk){
#pragma unroll
      for(int mi = 0; mi < 4; ++mi){
        int row = mi * 16 + l15;
        bf16x8 af = ld_frag(&KsB[cur][row * 64 + ((kk * 32 + g * 8) ^ ((row & 7) << 3))]);
        sa[mi] = __builtin_amdgcn_mfma_f32_16x16x32_bf16(af, bq[kk], sa[mi], 0, 0, 0);
      }
    }
    __builtin_amdgcn_s_setprio(0);

    float p[4][4];
    if((kt + 1) * 64 <= nkb){
#pragma unroll
      for(int mi = 0; mi < 4; ++mi)
#pragma unroll
        for(int r = 0; r < 4; ++r){
          p[mi][r] = __builtin_amdgcn_exp2f(sa[mi][r]);
          ll += p[mi][r];
        }
    } else {
      int kb0 = kt * 64 + g * 4;
#pragma unroll
      for(int mi = 0; mi < 4; ++mi)
#pragma unroll
        for(int r = 0; r < 4; ++r){
          float e = __builtin_amdgcn_exp2f(sa[mi][r]);
          p[mi][r] = (kb0 + mi * 16 + r < nkb) ? e : 0.f;
          ll += p[mi][r];
        }
    }

#pragma unroll
    for(int mi = 0; mi < 4; ++mi){
      unsigned d0, d1;
      asm("v_cvt_pk_bf16_f32 %0, %1, %2" : "=v"(d0) : "v"(p[mi][0]), "v"(p[mi][1]));
      asm("v_cvt_pk_bf16_f32 %0, %1, %2" : "=v"(d1) : "v"(p[mi][2]), "v"(p[mi][3]));
      u32x2 dd = {d0, d1};
      *(u32x2*)&Ps[w][l15 * 64 + ((mi * 16 + g * 4) ^ ((l15 & 7) << 3))] = dd;
    }

    __builtin_amdgcn_s_setprio(1);
#pragma unroll
    for(int kk = 0; kk < 2; ++kk){
      bf16x8 pb = ld_frag(&Ps[w][l15 * 64 + ((kk * 32 + g * 8) ^ ((l15 & 7) << 3))]);
#pragma unroll
      for(int mi = 0; mi < 4; ++mi){
        int row = mi * 16 + l15;
        bf16x8 av = ld_frag(&VtB[cur][row * 64 + ((kk * 32 + g * 8) ^ ((row & 7) << 3))]);
        acc[mi] = __builtin_amdgcn_mfma_f32_16x16x32_bf16(av, pb, acc[mi], 0, 0, 0);
      }
    }
    __builtin_amdgcn_s_setprio(0);

    __builtin_amdgcn_sched_barrier(0);
    __builtin_amdgcn_s_barrier();       // all waves done reading buf[cur]
    __builtin_amdgcn_sched_barrier(0);
    if(kt + 2 < nt) STAGE(kt + 2, cur);
  }

  ll += __shfl_xor(ll, 16);
  ll += __shfl_xor(ll, 32);
  float inv = 1.0f / ll;

  // epilogue: bounce all 128 O-rows through contiguous KsB[0..1] (16KB)
  unsigned short* Ob = &KsB[0][0];
  {
    int qrow = w * 16 + l15;            // 0..127
#pragma unroll
    for(int mi = 0; mi < 4; ++mi){
      us4 o;
#pragma unroll
      for(int r = 0; r < 4; ++r) o[r] = f2bf(acc[mi][r] * inv);
      *(us4*)&Ob[qrow * 64 + ((mi * 16 + g * 4) ^ ((qrow & 7) << 3))] = o;
    }
  }
  __syncthreads();
  {
    int qrow = tid >> 2, part = tid & 3;   // 128 rows x 4 parts
    us8 v0 = *(const us8*)&Ob[qrow * 64 + ((part * 16)     ^ ((qrow & 7) << 3))];
    us8 v1 = *(const us8*)&Ob[qrow * 64 + ((part * 16 + 8) ^ ((qrow & 7) << 3))];
    size_t orow = ((size_t)b * 2048 + qt * 128 + qrow) * 1024 + h * 64 + part * 16;
    *(us8*)&ctx[orow] = v0;
    *(us8*)&ctx[orow + 8] = v1;
  }
#undef STAGE
}

// ---------------- launch ----------------
extern "C" void kernel_launch(void* const* d_in, const int* in_sizes, int n_in,
                              void* d_out, int out_size, void* d_ws, size_t ws_size,
                              hipStream_t stream) {
  const float* Qf = (const float*)d_in[0];
  const float* Kf = (const float*)d_in[1];
  const float* Vf = (const float*)d_in[2];
  const int*   Mk = (const int*)d_in[3];
  const float* Wq = (const float*)d_in[4];
  const float* bq = (const float*)d_in[5];
  const float* Wk = (const float*)d_in[6];
  const float* bk = (const float*)d_in[7];
  const float* Wv = (const float*)d_in[8];
  const float* bv = (const float*)d_in[9];
  const float* Wo = (const float*)d_in[10];
  const float* bo = (const float*)d_in[11];

  const size_t MB = 1u << 20;
  char* ws = (char*)d_ws;
  unsigned short* Wqb = (unsigned short*)(ws + 0 * MB);
  unsigned short* Wkb = (unsigned short*)(ws + 2 * MB);
  unsigned short* Wvb = (unsigned short*)(ws + 4 * MB);
  unsigned short* Wob = (unsigned short*)(ws + 6 * MB);
  unsigned short* qs  = (unsigned short*)(ws + 8 * MB);
  unsigned short* ksc = (unsigned short*)(ws + 24 * MB);
  unsigned short* vTc = (unsigned short*)(ws + 40 * MB);
  unsigned short* ctx = (unsigned short*)(ws + 56 * MB);
  int* idx = (int*)(ws + 72 * MB);
  int* nk  = (int*)(ws + 73 * MB);
  unsigned short* Qb  = (unsigned short*)(ws + 74 * MB);
  unsigned short* Kbc = (unsigned short*)(ws + 90 * MB);
  unsigned short* Vbc = (unsigned short*)(ws + 106 * MB);

  mask_scan<<<4, 256, 0, stream>>>(Mk, idx, nk);
  cvt_all<<<dim3(4096, 7), 256, 0, stream>>>(Wq, Wk, Wv, Wo, Qf, Kf, Vf,
                                             Wqb, Wkb, Wvb, Wob, Qb, Kbc, Vbc,
                                             idx, nk);

  const float QSCALE = 0.125f * 1.4426950408889634f;  // 1/sqrt(d_head) * log2(e)
  dim3 blk(256);
  qkv_proj<<<dim3(64, 24), blk, 0, stream>>>(Qb, Kbc, Vbc, Wqb, Wkb, Wvb,
                                             bq, bk, bv, qs, ksc, vTc, QSCALE, nk);
  // 8-wave attention: grid (bh=64, qt=16), 512 threads
  attn_kernel<<<dim3(64, 16), 512, 0, stream>>>(qs, ksc, vTc, nk, ctx);
  gemm_out<<<dim3(64, 8), blk, 0, stream>>>(ctx, Wob, bo, (float*)d_out, 1024);
}

// Round 22
// 154.766 us; speedup vs baseline: 1.0690x; 1.0325x over previous
//
#include <hip/hip_runtime.h>

// MHA: BS=4 SEQ=2048 D_MODEL=1024 H=16 DH=64
// R22 = R21 + qkv_proj widened to 512-thread / 8-wave blocks (same move that
// won in attn R21): 128x128 tile, waves 2x4 (64x32 sub-tile each, acc[4][2]),
// counted-vmcnt pipeline with 4 gll16/lane per tile (vmcnt(4) steady).
// LDS 64KB -> 2 blocks x 8 waves = 16 waves/CU (2x R21's qkv occupancy).
// attn (8-wave, R21) / gemm_out (R19) / cvt_all / mask_scan unchanged.

typedef __attribute__((ext_vector_type(8))) unsigned short us8;
typedef __attribute__((ext_vector_type(4))) unsigned short us4;
typedef __attribute__((ext_vector_type(4))) int i4;
typedef __attribute__((ext_vector_type(4))) float f4;
typedef __attribute__((ext_vector_type(4))) float f32x4;
typedef __attribute__((ext_vector_type(8))) __bf16 bf16x8;
typedef __attribute__((ext_vector_type(2))) unsigned u32x2;
typedef __attribute__((ext_vector_type(4))) unsigned u32x4;

#define DEV static __device__ __forceinline__

DEV unsigned short f2bf(float f){
  unsigned u = __builtin_bit_cast(unsigned, f);
  u = (u + 0x7fffu + ((u >> 16) & 1u)) >> 16;
  return (unsigned short)u;
}

DEV bf16x8 ld_frag(const unsigned short* p){
  return __builtin_bit_cast(bf16x8, *(const us8*)p);
}

// async global->LDS, 16B per lane. LDS dest wave-uniform base + lane*16; global src per-lane.
DEV void gll16(const unsigned short* gsrc, unsigned short* ldst){
  __builtin_amdgcn_global_load_lds(
      (const __attribute__((address_space(1))) unsigned int*)gsrc,
      (__attribute__((address_space(3))) unsigned int*)ldst, 16, 0, 0);
}

// load 8 f32, convert to 8 bf16 via packed cvt (RNE)
DEV us8 ld_cvt_f32x8(const float* p){
  f4 v0 = *(const f4*)p;
  f4 v1 = *(const f4*)(p + 4);
  unsigned d0, d1, d2, d3;
  asm("v_cvt_pk_bf16_f32 %0, %1, %2" : "=v"(d0) : "v"(v0[0]), "v"(v0[1]));
  asm("v_cvt_pk_bf16_f32 %0, %1, %2" : "=v"(d1) : "v"(v0[2]), "v"(v0[3]));
  asm("v_cvt_pk_bf16_f32 %0, %1, %2" : "=v"(d2) : "v"(v1[0]), "v"(v1[1]));
  asm("v_cvt_pk_bf16_f32 %0, %1, %2" : "=v"(d3) : "v"(v1[2]), "v"(v1[3]));
  u32x4 u = {d0, d1, d2, d3};
  return __builtin_bit_cast(us8, u);
}

// ---------------- mask scan ----------------
__global__ __launch_bounds__(256) void mask_scan(
    const int* __restrict__ mask, int* __restrict__ idx, int* __restrict__ nk)
{
  const int b = blockIdx.x, t = threadIdx.x;
  __shared__ int sc[256];
  int m[8]; int c = 0;
#pragma unroll
  for(int r = 0; r < 8; ++r){ m[r] = mask[b * 2048 + t * 8 + r]; c += (m[r] != 0); }
  sc[t] = c;
  __syncthreads();
  for(int s = 1; s < 256; s <<= 1){
    int v = (t >= s) ? sc[t - s] : 0;
    __syncthreads();
    sc[t] += v;
    __syncthreads();
  }
  int pos = sc[t] - c;
  int total = sc[255];
#pragma unroll
  for(int r = 0; r < 8; ++r) if(m[r]) idx[b * 2048 + pos++] = t * 8 + r;
  int pend = (total + 127) & ~127;
  for(int p = total + t; p < pend; p += 256) idx[b * 2048 + p] = 0;
  if(t == 0) nk[b] = total;
}

// ---------------- one streaming conversion pass ----------------
__global__ __launch_bounds__(256) void cvt_all(
    const float* __restrict__ Wq, const float* __restrict__ Wk,
    const float* __restrict__ Wv, const float* __restrict__ Wo,
    const float* __restrict__ Qf, const float* __restrict__ Kf, const float* __restrict__ Vf,
    unsigned short* __restrict__ Wqb, unsigned short* __restrict__ Wkb,
    unsigned short* __restrict__ Wvb, unsigned short* __restrict__ Wob,
    unsigned short* __restrict__ Qb, unsigned short* __restrict__ Kbc,
    unsigned short* __restrict__ Vbc,
    const int* __restrict__ gidx, const int* __restrict__ nkarr)
{
  const int y = blockIdx.y, x = blockIdx.x, t = threadIdx.x;
  if(y < 4){
    if(x >= 512) return;
    const float* src = (y == 0) ? Wq : (y == 1) ? Wk : (y == 2) ? Wv : Wo;
    unsigned short* dst = (y == 0) ? Wqb : (y == 1) ? Wkb : (y == 2) ? Wvb : Wob;
    size_t i = (size_t)x * 2048 + t * 8;
    *(us8*)(dst + i) = ld_cvt_f32x8(src + i);
  } else if(y == 4){
    size_t i = (size_t)x * 2048 + t * 8;
    *(us8*)(Qb + i) = ld_cvt_f32x8(Qf + i);
  } else {
    const float* src = (y == 5) ? Kf : Vf;
    unsigned short* dst = (y == 5) ? Kbc : Vbc;
    int r0 = x * 2;
    int b = r0 >> 11, j = r0 & 2047;
    if(j >= ((nkarr[b] + 127) & ~127)) return;
    int rr = t >> 7;
    int srow = gidx[b * 2048 + j + rr];
    int col = (t & 127) * 8;
    *(us8*)(dst + (size_t)(r0 + rr) * 1024 + col) =
        ld_cvt_f32x8(src + ((size_t)b * 2048 + srow) * 1024 + col);
  }
}

// ---------------- Fused Q/K/V projection, 8-wave, counted-vmcnt pipeline ----------------
// 512 threads. Waves 2x4: wm = w>>2 (M half), wn = w&3 (N quarter).
// Per wave: 64x32 sub-tile, acc[4][2]. Staging: 4 gll16/lane per tile pair.
__global__ __launch_bounds__(512) void qkv_proj(
    const unsigned short* __restrict__ Qb, const unsigned short* __restrict__ Kbc,
    const unsigned short* __restrict__ Vbc,
    const unsigned short* __restrict__ Wqb, const unsigned short* __restrict__ Wkb,
    const unsigned short* __restrict__ Wvb,
    const float* __restrict__ bq, const float* __restrict__ bk, const float* __restrict__ bv,
    unsigned short* __restrict__ qs, unsigned short* __restrict__ ksc,
    unsigned short* __restrict__ vTc, float qscale, const int* __restrict__ nkarr)
{
  __shared__ __align__(16) unsigned short As[2][128 * 64];
  __shared__ __align__(16) unsigned short Bs[2][128 * 64];
  const int tid = threadIdx.x;
  const int x = blockIdx.x, z = blockIdx.y >> 3, ny = blockIdx.y & 7;
  const int w = tid >> 6, l = tid & 63, g = l >> 4, l15 = l & 15;
  const int wm = w >> 2, wn = w & 3;
  const int xsw = ((l & 7) ^ (l >> 3)) << 3;
  const int srow = (w << 3) + (l >> 3);             // wave w -> rows w*8..+7 (+64 for j=1)

  if(z >= 1){
    const int gb = (x * 128) >> 11, j0 = (x * 128) & 2047;
    if(j0 >= ((nkarr[gb] + 127) & ~127)) return;    // uniform exit, pre-barrier
  }

  const unsigned short* Ab = (z == 0) ? Qb : (z == 1) ? Kbc : Wvb;
  const unsigned short* Bb = (z == 0) ? Wqb : (z == 1) ? Wkb : Vbc;
  const int abase = (z == 2) ? ny * 128 : x * 128;
  const int bbase = (z == 2) ? x * 128 : ny * 128;

  f32x4 acc[4][2];
#pragma unroll
  for(int a = 0; a < 4; ++a)
#pragma unroll
    for(int b = 0; b < 2; ++b) acc[a][b] = (f32x4){0.f,0.f,0.f,0.f};

  auto STAGE = [&](int kt, int nb){   // 4 gll16 per lane
#pragma unroll
    for(int j = 0; j < 2; ++j)
      gll16(Ab + (size_t)(abase + srow + (j << 6)) * 1024 + kt * 64 + xsw,
            &As[nb][((w << 3) + (j << 6)) << 6]);
#pragma unroll
    for(int j = 0; j < 2; ++j)
      gll16(Bb + (size_t)(bbase + srow + (j << 6)) * 1024 + kt * 64 + xsw,
            &Bs[nb][((w << 3) + (j << 6)) << 6]);
  };

  STAGE(0, 0);
  STAGE(1, 1);

  for(int kt = 0; kt < 16; ++kt){
    const int cur = kt & 1;
    if(kt + 1 < 16) asm volatile("s_waitcnt vmcnt(4)" ::: "memory");
    else            asm volatile("s_waitcnt vmcnt(0)" ::: "memory");
    __builtin_amdgcn_sched_barrier(0);
    __builtin_amdgcn_s_barrier();       // tile-kt loads landed for all waves
    __builtin_amdgcn_sched_barrier(0);
#pragma unroll
    for(int kk = 0; kk < 2; ++kk){
      bf16x8 af[4], bg[2];
#pragma unroll
      for(int mi = 0; mi < 4; ++mi){
        int row = wm * 64 + mi * 16 + l15;
        af[mi] = ld_frag(&As[cur][row * 64 + ((kk * 32 + g * 8) ^ ((row & 7) << 3))]);
      }
#pragma unroll
      for(int ni = 0; ni < 2; ++ni){
        int row = wn * 32 + ni * 16 + l15;
        bg[ni] = ld_frag(&Bs[cur][row * 64 + ((kk * 32 + g * 8) ^ ((row & 7) << 3))]);
      }
#pragma unroll
      for(int mi = 0; mi < 4; ++mi)
#pragma unroll
        for(int ni = 0; ni < 2; ++ni)
          acc[mi][ni] = __builtin_amdgcn_mfma_f32_16x16x32_bf16(af[mi], bg[ni], acc[mi][ni], 0, 0, 0);
    }
    __builtin_amdgcn_sched_barrier(0);
    __builtin_amdgcn_s_barrier();       // all waves done reading buf[cur]
    __builtin_amdgcn_sched_barrier(0);
    if(kt + 2 < 16) STAGE(kt + 2, cur);
  }

  if(z < 2){
    const float scale = (z == 0) ? qscale : 1.0f;
    const float* bias = (z == 0) ? bq : bk;
    unsigned short* out = (z == 0) ? qs : ksc;
#pragma unroll
    for(int mi = 0; mi < 4; ++mi)
#pragma unroll
      for(int ni = 0; ni < 2; ++ni){
        int gmb = x * 128 + wm * 64 + mi * 16 + g * 4;
        int gn  = ny * 128 + wn * 32 + ni * 16 + l15;
#pragma unroll
        for(int r = 0; r < 4; ++r){
          int gm = gmb + r;
          float v = (acc[mi][ni][r] + bias[gn]) * scale;
          int b = gm >> 11, s = gm & 2047, h = gn >> 6, dh = gn & 63;
          out[(size_t)(((b << 4) + h) * 2048 + s) * 64 + dh] = f2bf(v);
        }
      }
  } else {
#pragma unroll
    for(int mi = 0; mi < 4; ++mi)
#pragma unroll
      for(int ni = 0; ni < 2; ++ni){
        int gmb = ny * 128 + wm * 64 + mi * 16 + g * 4;   // d index
        int gn  = x * 128 + wn * 32 + ni * 16 + l15;      // compacted s index
#pragma unroll
        for(int r = 0; r < 4; ++r){
          int gm = gmb + r;
          float v = acc[mi][ni][r] + bv[gm];
          int h = gm >> 6, dh = gm & 63, b = gn >> 11, s = gn & 2047;
          vTc[(size_t)(((b << 4) + h) * 64 + dh) * 2048 + s] = f2bf(v);
        }
      }
  }
}

// ---------------- out-proj GEMM, 2-deep counted-vmcnt pipeline (SWAPG; R19) ----------------
__global__ __launch_bounds__(256) void gemm_out(
    const unsigned short* __restrict__ Ap, const unsigned short* __restrict__ Bp,
    const float* __restrict__ bias, float* __restrict__ outp, int K)
{
  __shared__ __align__(16) unsigned short As[2][128 * 64];
  __shared__ __align__(16) unsigned short Bs[2][128 * 64];
  const int tid = threadIdx.x;
  const int gy = blockIdx.x, gx = blockIdx.y;      // SWAPG: M-tile = x
  const int w = tid >> 6, l = tid & 63, g = l >> 4, l15 = l & 15;
  const int wm = w >> 1, wn = w & 1;
  const int xsw = ((l & 7) ^ (l >> 3)) << 3;
  const int lrow = (w << 5) + (l >> 3);

  f32x4 acc[4][4];
#pragma unroll
  for(int a = 0; a < 4; ++a)
#pragma unroll
    for(int b = 0; b < 4; ++b) acc[a][b] = (f32x4){0.f,0.f,0.f,0.f};

  auto STAGE = [&](int kt, int nb){   // 8 gll16 per wave
#pragma unroll
    for(int j = 0; j < 4; ++j)
      gll16(Ap + (size_t)(gy * 128 + lrow + (j << 3)) * K + kt * 64 + xsw,
            &As[nb][((w << 5) + (j << 3)) << 6]);
#pragma unroll
    for(int j = 0; j < 4; ++j)
      gll16(Bp + (size_t)(gx * 128 + lrow + (j << 3)) * K + kt * 64 + xsw,
            &Bs[nb][((w << 5) + (j << 3)) << 6]);
  };

  const int nkt = K >> 6;
  STAGE(0, 0);
  STAGE(1, 1);

  for(int kt = 0; kt < nkt; ++kt){
    const int cur = kt & 1;
    if(kt + 1 < nkt) asm volatile("s_waitcnt vmcnt(8)" ::: "memory");
    else             asm volatile("s_waitcnt vmcnt(0)" ::: "memory");
    __builtin_amdgcn_sched_barrier(0);
    __builtin_amdgcn_s_barrier();
    __builtin_amdgcn_sched_barrier(0);
#pragma unroll
    for(int kk = 0; kk < 2; ++kk){
      bf16x8 af[4], bg[4];
#pragma unroll
      for(int mi = 0; mi < 4; ++mi){
        int row = wm * 64 + mi * 16 + l15;
        af[mi] = ld_frag(&As[cur][row * 64 + ((kk * 32 + g * 8) ^ ((row & 7) << 3))]);
      }
#pragma unroll
      for(int ni = 0; ni < 4; ++ni){
        int row = wn * 64 + ni * 16 + l15;
        bg[ni] = ld_frag(&Bs[cur][row * 64 + ((kk * 32 + g * 8) ^ ((row & 7) << 3))]);
      }
#pragma unroll
      for(int mi = 0; mi < 4; ++mi)
#pragma unroll
        for(int ni = 0; ni < 4; ++ni)
          acc[mi][ni] = __builtin_amdgcn_mfma_f32_16x16x32_bf16(af[mi], bg[ni], acc[mi][ni], 0, 0, 0);
    }
    __builtin_amdgcn_sched_barrier(0);
    __builtin_amdgcn_s_barrier();
    __builtin_amdgcn_sched_barrier(0);
    if(kt + 2 < nkt) STAGE(kt + 2, cur);
  }

#pragma unroll
  for(int mi = 0; mi < 4; ++mi)
#pragma unroll
    for(int ni = 0; ni < 4; ++ni){
      int gmb = gy * 128 + wm * 64 + mi * 16 + g * 4;
      int gn  = gx * 128 + wn * 64 + ni * 16 + l15;
#pragma unroll
      for(int r = 0; r < 4; ++r)
        outp[(size_t)(gmb + r) * 1024 + gn] = acc[mi][ni][r] + bias[gn];
    }
}

// ---------------- Flash attention, 8-wave blocks (R21-proven) ----------------
__global__ __launch_bounds__(512) void attn_kernel(
    const unsigned short* __restrict__ q, const unsigned short* __restrict__ ksc,
    const unsigned short* __restrict__ vTc, const int* __restrict__ nk,
    unsigned short* __restrict__ ctx)
{
  __shared__ __align__(16) unsigned short KsB[2][64 * 64];
  __shared__ __align__(16) unsigned short VtB[2][64 * 64];
  __shared__ __align__(16) unsigned short Ps[8][16 * 64];

  const int bh = blockIdx.x;            // bh fastest -> XCD co-location
  const int qt = blockIdx.y;            // 128-row q tile
  const int b  = bh >> 4, h = bh & 15;
  const int tid = threadIdx.x;
  const int w = tid >> 6, l = tid & 63, g = l >> 4, l15 = l & 15;

  const int nkb = nk[b];
  const int nt = (nkb + 63) >> 6;

  const unsigned short* qbase = q + ((size_t)(bh * 2048 + qt * 128 + w * 16 + l15)) * 64;
  bf16x8 bq[2];
  bq[0] = ld_frag(qbase + g * 8);
  bq[1] = ld_frag(qbase + 32 + g * 8);

  const unsigned short* kbase = ksc + (size_t)bh * 2048 * 64;
  const unsigned short* vbase = vTc + (size_t)bh * 64 * 2048;

  const int xsw = ((l & 7) ^ (l >> 3)) << 3;
  const unsigned short* kg0 = kbase + (size_t)((w << 3) + (l >> 3)) * 64 + xsw;
  const unsigned short* vg0 = vbase + (size_t)((w << 3) + (l >> 3)) * 2048 + xsw;
  const int kofs = (w << 3) << 6;

#define STAGE(kt_, bb_) do{                                    \
    gll16(kg0 + (size_t)(kt_) * 4096, &KsB[bb_][kofs]);        \
    gll16(vg0 + (size_t)(kt_) * 64,   &VtB[bb_][kofs]);        \
  }while(0)

  f32x4 acc[4];
#pragma unroll
  for(int mi = 0; mi < 4; ++mi) acc[mi] = (f32x4){0.f,0.f,0.f,0.f};
  float ll = 0.f;

  asm volatile("s_waitcnt vmcnt(0)" ::: "memory");
  STAGE(0, 0);
  if(nt > 1) STAGE(1, 1);

  for(int kt = 0; kt < nt; ++kt){
    const int cur = kt & 1;
    if(kt + 1 < nt) asm volatile("s_waitcnt vmcnt(2)" ::: "memory");
    else            asm volatile("s_waitcnt vmcnt(0)" ::: "memory");
    __builtin_amdgcn_sched_barrier(0);
    __builtin_amdgcn_s_barrier();
    __builtin_amdgcn_sched_barrier(0);

    f32x4 sa[4];
#pragma unroll
    for(int mi = 0; mi < 4; ++mi) sa[mi] = (f32x4){0.f,0.f,0.f,0.f};
    __builtin_amdgcn_s_setprio(1);
#pragma unroll
    for(int kk = 0; kk < 2; ++kk){
#pragma unroll
      for(int mi = 0; mi < 4; ++mi){
        int row = mi * 16 + l15;
        bf16x8 af = ld_frag(&KsB[cur][row * 64 + ((kk * 32 + g * 8) ^ ((row & 7) << 3))]);
        sa[mi] = __builtin_amdgcn_mfma_f32_16x16x32_bf16(af, bq[kk], sa[mi], 0, 0, 0);
      }
    }
    __builtin_amdgcn_s_setprio(0);

    float p[4][4];
    if((kt + 1) * 64 <= nkb){
#pragma unroll
      for(int mi = 0; mi < 4; ++mi)
#pragma unroll
        for(int r = 0; r < 4; ++r){
          p[mi][r] = __builtin_amdgcn_exp2f(sa[mi][r]);
          ll += p[mi][r];
        }
    } else {
      int kb0 = kt * 64 + g * 4;
#pragma unroll
      for(int mi = 0; mi < 4; ++mi)
#pragma unroll
        for(int r = 0; r < 4; ++r){
          float e = __builtin_amdgcn_exp2f(sa[mi][r]);
          p[mi][r] = (kb0 + mi * 16 + r < nkb) ? e : 0.f;
          ll += p[mi][r];
        }
    }

#pragma unroll
    for(int mi = 0; mi < 4; ++mi){
      unsigned d0, d1;
      asm("v_cvt_pk_bf16_f32 %0, %1, %2" : "=v"(d0) : "v"(p[mi][0]), "v"(p[mi][1]));
      asm("v_cvt_pk_bf16_f32 %0, %1, %2" : "=v"(d1) : "v"(p[mi][2]), "v"(p[mi][3]));
      u32x2 dd = {d0, d1};
      *(u32x2*)&Ps[w][l15 * 64 + ((mi * 16 + g * 4) ^ ((l15 & 7) << 3))] = dd;
    }

    __builtin_amdgcn_s_setprio(1);
#pragma unroll
    for(int kk = 0; kk < 2; ++kk){
      bf16x8 pb = ld_frag(&Ps[w][l15 * 64 + ((kk * 32 + g * 8) ^ ((l15 & 7) << 3))]);
#pragma unroll
      for(int mi = 0; mi < 4; ++mi){
        int row = mi * 16 + l15;
        bf16x8 av = ld_frag(&VtB[cur][row * 64 + ((kk * 32 + g * 8) ^ ((row & 7) << 3))]);
        acc[mi] = __builtin_amdgcn_mfma_f32_16x16x32_bf16(av, pb, acc[mi], 0, 0, 0);
      }
    }
    __builtin_amdgcn_s_setprio(0);

    __builtin_amdgcn_sched_barrier(0);
    __builtin_amdgcn_s_barrier();
    __builtin_amdgcn_sched_barrier(0);
    if(kt + 2 < nt) STAGE(kt + 2, cur);
  }

  ll += __shfl_xor(ll, 16);
  ll += __shfl_xor(ll, 32);
  float inv = 1.0f / ll;

  unsigned short* Ob = &KsB[0][0];
  {
    int qrow = w * 16 + l15;
#pragma unroll
    for(int mi = 0; mi < 4; ++mi){
      us4 o;
#pragma unroll
      for(int r = 0; r < 4; ++r) o[r] = f2bf(acc[mi][r] * inv);
      *(us4*)&Ob[qrow * 64 + ((mi * 16 + g * 4) ^ ((qrow & 7) << 3))] = o;
    }
  }
  __syncthreads();
  {
    int qrow = tid >> 2, part = tid & 3;
    us8 v0 = *(const us8*)&Ob[qrow * 64 + ((part * 16)     ^ ((qrow & 7) << 3))];
    us8 v1 = *(const us8*)&Ob[qrow * 64 + ((part * 16 + 8) ^ ((qrow & 7) << 3))];
    size_t orow = ((size_t)b * 2048 + qt * 128 + qrow) * 1024 + h * 64 + part * 16;
    *(us8*)&ctx[orow] = v0;
    *(us8*)&ctx[orow + 8] = v1;
  }
#undef STAGE
}

// ---------------- launch ----------------
extern "C" void kernel_launch(void* const* d_in, const int* in_sizes, int n_in,
                              void* d_out, int out_size, void* d_ws, size_t ws_size,
                              hipStream_t stream) {
  const float* Qf = (const float*)d_in[0];
  const float* Kf = (const float*)d_in[1];
  const float* Vf = (const float*)d_in[2];
  const int*   Mk = (const int*)d_in[3];
  const float* Wq = (const float*)d_in[4];
  const float* bq = (const float*)d_in[5];
  const float* Wk = (const float*)d_in[6];
  const float* bk = (const float*)d_in[7];
  const float* Wv = (const float*)d_in[8];
  const float* bv = (const float*)d_in[9];
  const float* Wo = (const float*)d_in[10];
  const float* bo = (const float*)d_in[11];

  const size_t MB = 1u << 20;
  char* ws = (char*)d_ws;
  unsigned short* Wqb = (unsigned short*)(ws + 0 * MB);
  unsigned short* Wkb = (unsigned short*)(ws + 2 * MB);
  unsigned short* Wvb = (unsigned short*)(ws + 4 * MB);
  unsigned short* Wob = (unsigned short*)(ws + 6 * MB);
  unsigned short* qs  = (unsigned short*)(ws + 8 * MB);
  unsigned short* ksc = (unsigned short*)(ws + 24 * MB);
  unsigned short* vTc = (unsigned short*)(ws + 40 * MB);
  unsigned short* ctx = (unsigned short*)(ws + 56 * MB);
  int* idx = (int*)(ws + 72 * MB);
  int* nk  = (int*)(ws + 73 * MB);
  unsigned short* Qb  = (unsigned short*)(ws + 74 * MB);
  unsigned short* Kbc = (unsigned short*)(ws + 90 * MB);
  unsigned short* Vbc = (unsigned short*)(ws + 106 * MB);

  mask_scan<<<4, 256, 0, stream>>>(Mk, idx, nk);
  cvt_all<<<dim3(4096, 7), 256, 0, stream>>>(Wq, Wk, Wv, Wo, Qf, Kf, Vf,
                                             Wqb, Wkb, Wvb, Wob, Qb, Kbc, Vbc,
                                             idx, nk);

  const float QSCALE = 0.125f * 1.4426950408889634f;  // 1/sqrt(d_head) * log2(e)
  // 8-wave fused Q/K/V: grid (64, 24), 512 threads
  qkv_proj<<<dim3(64, 24), 512, 0, stream>>>(Qb, Kbc, Vbc, Wqb, Wkb, Wvb,
                                             bq, bk, bv, qs, ksc, vTc, QSCALE, nk);
  // 8-wave attention: grid (bh=64, qt=16), 512 threads
  attn_kernel<<<dim3(64, 16), 512, 0, stream>>>(qs, ksc, vTc, nk, ctx);
  gemm_out<<<dim3(64, 8), 256, 0, stream>>>(ctx, Wob, bo, (float*)d_out, 1024);
}

// Round 23
// 154.350 us; speedup vs baseline: 1.0719x; 1.0027x over previous
//
#include <hip/hip_runtime.h>

// MHA: BS=4 SEQ=2048 D_MODEL=1024 H=16 DH=64
// R23 = R22 + gemm_out widened to 512-thread / 8-wave blocks (3x-proven move):
// waves 2x4 (64x32 sub-tile, acc[4][2]), 4 gll16/lane/tile, vmcnt(4) counted
// pipeline, LDS 64KB -> 16 waves/CU. qkv/attn/cvt/scan = R22 (proven).

typedef __attribute__((ext_vector_type(8))) unsigned short us8;
typedef __attribute__((ext_vector_type(4))) unsigned short us4;
typedef __attribute__((ext_vector_type(4))) int i4;
typedef __attribute__((ext_vector_type(4))) float f4;
typedef __attribute__((ext_vector_type(4))) float f32x4;
typedef __attribute__((ext_vector_type(8))) __bf16 bf16x8;
typedef __attribute__((ext_vector_type(2))) unsigned u32x2;
typedef __attribute__((ext_vector_type(4))) unsigned u32x4;

#define DEV static __device__ __forceinline__

DEV unsigned short f2bf(float f){
  unsigned u = __builtin_bit_cast(unsigned, f);
  u = (u + 0x7fffu + ((u >> 16) & 1u)) >> 16;
  return (unsigned short)u;
}

DEV bf16x8 ld_frag(const unsigned short* p){
  return __builtin_bit_cast(bf16x8, *(const us8*)p);
}

// async global->LDS, 16B per lane. LDS dest wave-uniform base + lane*16; global src per-lane.
DEV void gll16(const unsigned short* gsrc, unsigned short* ldst){
  __builtin_amdgcn_global_load_lds(
      (const __attribute__((address_space(1))) unsigned int*)gsrc,
      (__attribute__((address_space(3))) unsigned int*)ldst, 16, 0, 0);
}

// load 8 f32, convert to 8 bf16 via packed cvt (RNE)
DEV us8 ld_cvt_f32x8(const float* p){
  f4 v0 = *(const f4*)p;
  f4 v1 = *(const f4*)(p + 4);
  unsigned d0, d1, d2, d3;
  asm("v_cvt_pk_bf16_f32 %0, %1, %2" : "=v"(d0) : "v"(v0[0]), "v"(v0[1]));
  asm("v_cvt_pk_bf16_f32 %0, %1, %2" : "=v"(d1) : "v"(v0[2]), "v"(v0[3]));
  asm("v_cvt_pk_bf16_f32 %0, %1, %2" : "=v"(d2) : "v"(v1[0]), "v"(v1[1]));
  asm("v_cvt_pk_bf16_f32 %0, %1, %2" : "=v"(d3) : "v"(v1[2]), "v"(v1[3]));
  u32x4 u = {d0, d1, d2, d3};
  return __builtin_bit_cast(us8, u);
}

// ---------------- mask scan ----------------
__global__ __launch_bounds__(256) void mask_scan(
    const int* __restrict__ mask, int* __restrict__ idx, int* __restrict__ nk)
{
  const int b = blockIdx.x, t = threadIdx.x;
  __shared__ int sc[256];
  int m[8]; int c = 0;
#pragma unroll
  for(int r = 0; r < 8; ++r){ m[r] = mask[b * 2048 + t * 8 + r]; c += (m[r] != 0); }
  sc[t] = c;
  __syncthreads();
  for(int s = 1; s < 256; s <<= 1){
    int v = (t >= s) ? sc[t - s] : 0;
    __syncthreads();
    sc[t] += v;
    __syncthreads();
  }
  int pos = sc[t] - c;
  int total = sc[255];
#pragma unroll
  for(int r = 0; r < 8; ++r) if(m[r]) idx[b * 2048 + pos++] = t * 8 + r;
  int pend = (total + 127) & ~127;
  for(int p = total + t; p < pend; p += 256) idx[b * 2048 + p] = 0;
  if(t == 0) nk[b] = total;
}

// ---------------- one streaming conversion pass ----------------
__global__ __launch_bounds__(256) void cvt_all(
    const float* __restrict__ Wq, const float* __restrict__ Wk,
    const float* __restrict__ Wv, const float* __restrict__ Wo,
    const float* __restrict__ Qf, const float* __restrict__ Kf, const float* __restrict__ Vf,
    unsigned short* __restrict__ Wqb, unsigned short* __restrict__ Wkb,
    unsigned short* __restrict__ Wvb, unsigned short* __restrict__ Wob,
    unsigned short* __restrict__ Qb, unsigned short* __restrict__ Kbc,
    unsigned short* __restrict__ Vbc,
    const int* __restrict__ gidx, const int* __restrict__ nkarr)
{
  const int y = blockIdx.y, x = blockIdx.x, t = threadIdx.x;
  if(y < 4){
    if(x >= 512) return;
    const float* src = (y == 0) ? Wq : (y == 1) ? Wk : (y == 2) ? Wv : Wo;
    unsigned short* dst = (y == 0) ? Wqb : (y == 1) ? Wkb : (y == 2) ? Wvb : Wob;
    size_t i = (size_t)x * 2048 + t * 8;
    *(us8*)(dst + i) = ld_cvt_f32x8(src + i);
  } else if(y == 4){
    size_t i = (size_t)x * 2048 + t * 8;
    *(us8*)(Qb + i) = ld_cvt_f32x8(Qf + i);
  } else {
    const float* src = (y == 5) ? Kf : Vf;
    unsigned short* dst = (y == 5) ? Kbc : Vbc;
    int r0 = x * 2;
    int b = r0 >> 11, j = r0 & 2047;
    if(j >= ((nkarr[b] + 127) & ~127)) return;
    int rr = t >> 7;
    int srow = gidx[b * 2048 + j + rr];
    int col = (t & 127) * 8;
    *(us8*)(dst + (size_t)(r0 + rr) * 1024 + col) =
        ld_cvt_f32x8(src + ((size_t)b * 2048 + srow) * 1024 + col);
  }
}

// ---------------- Fused Q/K/V projection, 8-wave, counted-vmcnt (R22) ----------------
__global__ __launch_bounds__(512) void qkv_proj(
    const unsigned short* __restrict__ Qb, const unsigned short* __restrict__ Kbc,
    const unsigned short* __restrict__ Vbc,
    const unsigned short* __restrict__ Wqb, const unsigned short* __restrict__ Wkb,
    const unsigned short* __restrict__ Wvb,
    const float* __restrict__ bq, const float* __restrict__ bk, const float* __restrict__ bv,
    unsigned short* __restrict__ qs, unsigned short* __restrict__ ksc,
    unsigned short* __restrict__ vTc, float qscale, const int* __restrict__ nkarr)
{
  __shared__ __align__(16) unsigned short As[2][128 * 64];
  __shared__ __align__(16) unsigned short Bs[2][128 * 64];
  const int tid = threadIdx.x;
  const int x = blockIdx.x, z = blockIdx.y >> 3, ny = blockIdx.y & 7;
  const int w = tid >> 6, l = tid & 63, g = l >> 4, l15 = l & 15;
  const int wm = w >> 2, wn = w & 3;
  const int xsw = ((l & 7) ^ (l >> 3)) << 3;
  const int srow = (w << 3) + (l >> 3);

  if(z >= 1){
    const int gb = (x * 128) >> 11, j0 = (x * 128) & 2047;
    if(j0 >= ((nkarr[gb] + 127) & ~127)) return;    // uniform exit, pre-barrier
  }

  const unsigned short* Ab = (z == 0) ? Qb : (z == 1) ? Kbc : Wvb;
  const unsigned short* Bb = (z == 0) ? Wqb : (z == 1) ? Wkb : Vbc;
  const int abase = (z == 2) ? ny * 128 : x * 128;
  const int bbase = (z == 2) ? x * 128 : ny * 128;

  f32x4 acc[4][2];
#pragma unroll
  for(int a = 0; a < 4; ++a)
#pragma unroll
    for(int b = 0; b < 2; ++b) acc[a][b] = (f32x4){0.f,0.f,0.f,0.f};

  auto STAGE = [&](int kt, int nb){   // 4 gll16 per lane
#pragma unroll
    for(int j = 0; j < 2; ++j)
      gll16(Ab + (size_t)(abase + srow + (j << 6)) * 1024 + kt * 64 + xsw,
            &As[nb][((w << 3) + (j << 6)) << 6]);
#pragma unroll
    for(int j = 0; j < 2; ++j)
      gll16(Bb + (size_t)(bbase + srow + (j << 6)) * 1024 + kt * 64 + xsw,
            &Bs[nb][((w << 3) + (j << 6)) << 6]);
  };

  STAGE(0, 0);
  STAGE(1, 1);

  for(int kt = 0; kt < 16; ++kt){
    const int cur = kt & 1;
    if(kt + 1 < 16) asm volatile("s_waitcnt vmcnt(4)" ::: "memory");
    else            asm volatile("s_waitcnt vmcnt(0)" ::: "memory");
    __builtin_amdgcn_sched_barrier(0);
    __builtin_amdgcn_s_barrier();
    __builtin_amdgcn_sched_barrier(0);
#pragma unroll
    for(int kk = 0; kk < 2; ++kk){
      bf16x8 af[4], bg[2];
#pragma unroll
      for(int mi = 0; mi < 4; ++mi){
        int row = wm * 64 + mi * 16 + l15;
        af[mi] = ld_frag(&As[cur][row * 64 + ((kk * 32 + g * 8) ^ ((row & 7) << 3))]);
      }
#pragma unroll
      for(int ni = 0; ni < 2; ++ni){
        int row = wn * 32 + ni * 16 + l15;
        bg[ni] = ld_frag(&Bs[cur][row * 64 + ((kk * 32 + g * 8) ^ ((row & 7) << 3))]);
      }
#pragma unroll
      for(int mi = 0; mi < 4; ++mi)
#pragma unroll
        for(int ni = 0; ni < 2; ++ni)
          acc[mi][ni] = __builtin_amdgcn_mfma_f32_16x16x32_bf16(af[mi], bg[ni], acc[mi][ni], 0, 0, 0);
    }
    __builtin_amdgcn_sched_barrier(0);
    __builtin_amdgcn_s_barrier();
    __builtin_amdgcn_sched_barrier(0);
    if(kt + 2 < 16) STAGE(kt + 2, cur);
  }

  if(z < 2){
    const float scale = (z == 0) ? qscale : 1.0f;
    const float* bias = (z == 0) ? bq : bk;
    unsigned short* out = (z == 0) ? qs : ksc;
#pragma unroll
    for(int mi = 0; mi < 4; ++mi)
#pragma unroll
      for(int ni = 0; ni < 2; ++ni){
        int gmb = x * 128 + wm * 64 + mi * 16 + g * 4;
        int gn  = ny * 128 + wn * 32 + ni * 16 + l15;
#pragma unroll
        for(int r = 0; r < 4; ++r){
          int gm = gmb + r;
          float v = (acc[mi][ni][r] + bias[gn]) * scale;
          int b = gm >> 11, s = gm & 2047, h = gn >> 6, dh = gn & 63;
          out[(size_t)(((b << 4) + h) * 2048 + s) * 64 + dh] = f2bf(v);
        }
      }
  } else {
#pragma unroll
    for(int mi = 0; mi < 4; ++mi)
#pragma unroll
      for(int ni = 0; ni < 2; ++ni){
        int gmb = ny * 128 + wm * 64 + mi * 16 + g * 4;   // d index
        int gn  = x * 128 + wn * 32 + ni * 16 + l15;      // compacted s index
#pragma unroll
        for(int r = 0; r < 4; ++r){
          int gm = gmb + r;
          float v = acc[mi][ni][r] + bv[gm];
          int h = gm >> 6, dh = gm & 63, b = gn >> 11, s = gn & 2047;
          vTc[(size_t)(((b << 4) + h) * 64 + dh) * 2048 + s] = f2bf(v);
        }
      }
  }
}

// ---------------- out-proj GEMM, 8-wave, counted-vmcnt pipeline (SWAPG) ----------------
// 512 threads. Waves 2x4: wm = w>>2, wn = w&3. 64x32 sub-tile, acc[4][2].
__global__ __launch_bounds__(512) void gemm_out(
    const unsigned short* __restrict__ Ap, const unsigned short* __restrict__ Bp,
    const float* __restrict__ bias, float* __restrict__ outp, int K)
{
  __shared__ __align__(16) unsigned short As[2][128 * 64];
  __shared__ __align__(16) unsigned short Bs[2][128 * 64];
  const int tid = threadIdx.x;
  const int gy = blockIdx.x, gx = blockIdx.y;      // SWAPG: M-tile = x
  const int w = tid >> 6, l = tid & 63, g = l >> 4, l15 = l & 15;
  const int wm = w >> 2, wn = w & 3;
  const int xsw = ((l & 7) ^ (l >> 3)) << 3;
  const int srow = (w << 3) + (l >> 3);

  f32x4 acc[4][2];
#pragma unroll
  for(int a = 0; a < 4; ++a)
#pragma unroll
    for(int b = 0; b < 2; ++b) acc[a][b] = (f32x4){0.f,0.f,0.f,0.f};

  auto STAGE = [&](int kt, int nb){   // 4 gll16 per lane
#pragma unroll
    for(int j = 0; j < 2; ++j)
      gll16(Ap + (size_t)(gy * 128 + srow + (j << 6)) * K + kt * 64 + xsw,
            &As[nb][((w << 3) + (j << 6)) << 6]);
#pragma unroll
    for(int j = 0; j < 2; ++j)
      gll16(Bp + (size_t)(gx * 128 + srow + (j << 6)) * K + kt * 64 + xsw,
            &Bs[nb][((w << 3) + (j << 6)) << 6]);
  };

  const int nkt = K >> 6;
  STAGE(0, 0);
  STAGE(1, 1);

  for(int kt = 0; kt < nkt; ++kt){
    const int cur = kt & 1;
    if(kt + 1 < nkt) asm volatile("s_waitcnt vmcnt(4)" ::: "memory");
    else             asm volatile("s_waitcnt vmcnt(0)" ::: "memory");
    __builtin_amdgcn_sched_barrier(0);
    __builtin_amdgcn_s_barrier();
    __builtin_amdgcn_sched_barrier(0);
#pragma unroll
    for(int kk = 0; kk < 2; ++kk){
      bf16x8 af[4], bg[2];
#pragma unroll
      for(int mi = 0; mi < 4; ++mi){
        int row = wm * 64 + mi * 16 + l15;
        af[mi] = ld_frag(&As[cur][row * 64 + ((kk * 32 + g * 8) ^ ((row & 7) << 3))]);
      }
#pragma unroll
      for(int ni = 0; ni < 2; ++ni){
        int row = wn * 32 + ni * 16 + l15;
        bg[ni] = ld_frag(&Bs[cur][row * 64 + ((kk * 32 + g * 8) ^ ((row & 7) << 3))]);
      }
#pragma unroll
      for(int mi = 0; mi < 4; ++mi)
#pragma unroll
        for(int ni = 0; ni < 2; ++ni)
          acc[mi][ni] = __builtin_amdgcn_mfma_f32_16x16x32_bf16(af[mi], bg[ni], acc[mi][ni], 0, 0, 0);
    }
    __builtin_amdgcn_sched_barrier(0);
    __builtin_amdgcn_s_barrier();
    __builtin_amdgcn_sched_barrier(0);
    if(kt + 2 < nkt) STAGE(kt + 2, cur);
  }

#pragma unroll
  for(int mi = 0; mi < 4; ++mi)
#pragma unroll
    for(int ni = 0; ni < 2; ++ni){
      int gmb = gy * 128 + wm * 64 + mi * 16 + g * 4;
      int gn  = gx * 128 + wn * 32 + ni * 16 + l15;
#pragma unroll
      for(int r = 0; r < 4; ++r)
        outp[(size_t)(gmb + r) * 1024 + gn] = acc[mi][ni][r] + bias[gn];
    }
}

// ---------------- Flash attention, 8-wave blocks (R21/R22-proven) ----------------
__global__ __launch_bounds__(512) void attn_kernel(
    const unsigned short* __restrict__ q, const unsigned short* __restrict__ ksc,
    const unsigned short* __restrict__ vTc, const int* __restrict__ nk,
    unsigned short* __restrict__ ctx)
{
  __shared__ __align__(16) unsigned short KsB[2][64 * 64];
  __shared__ __align__(16) unsigned short VtB[2][64 * 64];
  __shared__ __align__(16) unsigned short Ps[8][16 * 64];

  const int bh = blockIdx.x;            // bh fastest -> XCD co-location
  const int qt = blockIdx.y;            // 128-row q tile
  const int b  = bh >> 4, h = bh & 15;
  const int tid = threadIdx.x;
  const int w = tid >> 6, l = tid & 63, g = l >> 4, l15 = l & 15;

  const int nkb = nk[b];
  const int nt = (nkb + 63) >> 6;

  const unsigned short* qbase = q + ((size_t)(bh * 2048 + qt * 128 + w * 16 + l15)) * 64;
  bf16x8 bq[2];
  bq[0] = ld_frag(qbase + g * 8);
  bq[1] = ld_frag(qbase + 32 + g * 8);

  const unsigned short* kbase = ksc + (size_t)bh * 2048 * 64;
  const unsigned short* vbase = vTc + (size_t)bh * 64 * 2048;

  const int xsw = ((l & 7) ^ (l >> 3)) << 3;
  const unsigned short* kg0 = kbase + (size_t)((w << 3) + (l >> 3)) * 64 + xsw;
  const unsigned short* vg0 = vbase + (size_t)((w << 3) + (l >> 3)) * 2048 + xsw;
  const int kofs = (w << 3) << 6;

#define STAGE(kt_, bb_) do{                                    \
    gll16(kg0 + (size_t)(kt_) * 4096, &KsB[bb_][kofs]);        \
    gll16(vg0 + (size_t)(kt_) * 64,   &VtB[bb_][kofs]);        \
  }while(0)

  f32x4 acc[4];
#pragma unroll
  for(int mi = 0; mi < 4; ++mi) acc[mi] = (f32x4){0.f,0.f,0.f,0.f};
  float ll = 0.f;

  asm volatile("s_waitcnt vmcnt(0)" ::: "memory");
  STAGE(0, 0);
  if(nt > 1) STAGE(1, 1);

  for(int kt = 0; kt < nt; ++kt){
    const int cur = kt & 1;
    if(kt + 1 < nt) asm volatile("s_waitcnt vmcnt(2)" ::: "memory");
    else            asm volatile("s_waitcnt vmcnt(0)" ::: "memory");
    __builtin_amdgcn_sched_barrier(0);
    __builtin_amdgcn_s_barrier();
    __builtin_amdgcn_sched_barrier(0);

    f32x4 sa[4];
#pragma unroll
    for(int mi = 0; mi < 4; ++mi) sa[mi] = (f32x4){0.f,0.f,0.f,0.f};
    __builtin_amdgcn_s_setprio(1);
#pragma unroll
    for(int kk = 0; kk < 2; ++kk){
#pragma unroll
      for(int mi = 0; mi < 4; ++mi){
        int row = mi * 16 + l15;
        bf16x8 af = ld_frag(&KsB[cur][row * 64 + ((kk * 32 + g * 8) ^ ((row & 7) << 3))]);
        sa[mi] = __builtin_amdgcn_mfma_f32_16x16x32_bf16(af, bq[kk], sa[mi], 0, 0, 0);
      }
    }
    __builtin_amdgcn_s_setprio(0);

    float p[4][4];
    if((kt + 1) * 64 <= nkb){
#pragma unroll
      for(int mi = 0; mi < 4; ++mi)
#pragma unroll
        for(int r = 0; r < 4; ++r){
          p[mi][r] = __builtin_amdgcn_exp2f(sa[mi][r]);
          ll += p[mi][r];
        }
    } else {
      int kb0 = kt * 64 + g * 4;
#pragma unroll
      for(int mi = 0; mi < 4; ++mi)
#pragma unroll
        for(int r = 0; r < 4; ++r){
          float e = __builtin_amdgcn_exp2f(sa[mi][r]);
          p[mi][r] = (kb0 + mi * 16 + r < nkb) ? e : 0.f;
          ll += p[mi][r];
        }
    }

#pragma unroll
    for(int mi = 0; mi < 4; ++mi){
      unsigned d0, d1;
      asm("v_cvt_pk_bf16_f32 %0, %1, %2" : "=v"(d0) : "v"(p[mi][0]), "v"(p[mi][1]));
      asm("v_cvt_pk_bf16_f32 %0, %1, %2" : "=v"(d1) : "v"(p[mi][2]), "v"(p[mi][3]));
      u32x2 dd = {d0, d1};
      *(u32x2*)&Ps[w][l15 * 64 + ((mi * 16 + g * 4) ^ ((l15 & 7) << 3))] = dd;
    }

    __builtin_amdgcn_s_setprio(1);
#pragma unroll
    for(int kk = 0; kk < 2; ++kk){
      bf16x8 pb = ld_frag(&Ps[w][l15 * 64 + ((kk * 32 + g * 8) ^ ((l15 & 7) << 3))]);
#pragma unroll
      for(int mi = 0; mi < 4; ++mi){
        int row = mi * 16 + l15;
        bf16x8 av = ld_frag(&VtB[cur][row * 64 + ((kk * 32 + g * 8) ^ ((row & 7) << 3))]);
        acc[mi] = __builtin_amdgcn_mfma_f32_16x16x32_bf16(av, pb, acc[mi], 0, 0, 0);
      }
    }
    __builtin_amdgcn_s_setprio(0);

    __builtin_amdgcn_sched_barrier(0);
    __builtin_amdgcn_s_barrier();
    __builtin_amdgcn_sched_barrier(0);
    if(kt + 2 < nt) STAGE(kt + 2, cur);
  }

  ll += __shfl_xor(ll, 16);
  ll += __shfl_xor(ll, 32);
  float inv = 1.0f / ll;

  unsigned short* Ob = &KsB[0][0];
  {
    int qrow = w * 16 + l15;
#pragma unroll
    for(int mi = 0; mi < 4; ++mi){
      us4 o;
#pragma unroll
      for(int r = 0; r < 4; ++r) o[r] = f2bf(acc[mi][r] * inv);
      *(us4*)&Ob[qrow * 64 + ((mi * 16 + g * 4) ^ ((qrow & 7) << 3))] = o;
    }
  }
  __syncthreads();
  {
    int qrow = tid >> 2, part = tid & 3;
    us8 v0 = *(const us8*)&Ob[qrow * 64 + ((part * 16)     ^ ((qrow & 7) << 3))];
    us8 v1 = *(const us8*)&Ob[qrow * 64 + ((part * 16 + 8) ^ ((qrow & 7) << 3))];
    size_t orow = ((size_t)b * 2048 + qt * 128 + qrow) * 1024 + h * 64 + part * 16;
    *(us8*)&ctx[orow] = v0;
    *(us8*)&ctx[orow + 8] = v1;
  }
#undef STAGE
}

// ---------------- launch ----------------
extern "C" void kernel_launch(void* const* d_in, const int* in_sizes, int n_in,
                              void* d_out, int out_size, void* d_ws, size_t ws_size,
                              hipStream_t stream) {
  const float* Qf = (const float*)d_in[0];
  const float* Kf = (const float*)d_in[1];
  const float* Vf = (const float*)d_in[2];
  const int*   Mk = (const int*)d_in[3];
  const float* Wq = (const float*)d_in[4];
  const float* bq = (const float*)d_in[5];
  const float* Wk = (const float*)d_in[6];
  const float* bk = (const float*)d_in[7];
  const float* Wv = (const float*)d_in[8];
  const float* bv = (const float*)d_in[9];
  const float* Wo = (const float*)d_in[10];
  const float* bo = (const float*)d_in[11];

  const size_t MB = 1u << 20;
  char* ws = (char*)d_ws;
  unsigned short* Wqb = (unsigned short*)(ws + 0 * MB);
  unsigned short* Wkb = (unsigned short*)(ws + 2 * MB);
  unsigned short* Wvb = (unsigned short*)(ws + 4 * MB);
  unsigned short* Wob = (unsigned short*)(ws + 6 * MB);
  unsigned short* qs  = (unsigned short*)(ws + 8 * MB);
  unsigned short* ksc = (unsigned short*)(ws + 24 * MB);
  unsigned short* vTc = (unsigned short*)(ws + 40 * MB);
  unsigned short* ctx = (unsigned short*)(ws + 56 * MB);
  int* idx = (int*)(ws + 72 * MB);
  int* nk  = (int*)(ws + 73 * MB);
  unsigned short* Qb  = (unsigned short*)(ws + 74 * MB);
  unsigned short* Kbc = (unsigned short*)(ws + 90 * MB);
  unsigned short* Vbc = (unsigned short*)(ws + 106 * MB);

  mask_scan<<<4, 256, 0, stream>>>(Mk, idx, nk);
  cvt_all<<<dim3(4096, 7), 256, 0, stream>>>(Wq, Wk, Wv, Wo, Qf, Kf, Vf,
                                             Wqb, Wkb, Wvb, Wob, Qb, Kbc, Vbc,
                                             idx, nk);

  const float QSCALE = 0.125f * 1.4426950408889634f;  // 1/sqrt(d_head) * log2(e)
  qkv_proj<<<dim3(64, 24), 512, 0, stream>>>(Qb, Kbc, Vbc, Wqb, Wkb, Wvb,
                                             bq, bk, bv, qs, ksc, vTc, QSCALE, nk);
  attn_kernel<<<dim3(64, 16), 512, 0, stream>>>(qs, ksc, vTc, nk, ctx);
  gemm_out<<<dim3(64, 8), 512, 0, stream>>>(ctx, Wob, bo, (float*)d_out, 1024);
}